// Round 1
// baseline (124.060 us; speedup 1.0000x reference)
//
#include <hip/hip_runtime.h>
#include <hip/hip_bf16.h>

// GuideAttentionModule: out = softmax((Q+tQ)(K+tK)^T/8) V, fused via
//   xt = x + tokens;  cQ = (xt@Wq.T + 2bq)/8 ; cK = xt@Wk.T + 2bk ; Vt = (x@Wv.T + bv)^T
// All GEMMs bf16-MFMA 16x16x32 with fp32 accumulation; flash attention with
// online softmax in fp32. fp32 output.

typedef __bf16 bf16;
typedef __bf16 bf16x8 __attribute__((ext_vector_type(8)));
typedef float  f32x4  __attribute__((ext_vector_type(4)));

#define LOG2E 1.4426950408889634f

__device__ __forceinline__ void gll16(const void* g, void* l) {
  __builtin_amdgcn_global_load_lds(
      (const __attribute__((address_space(1))) unsigned int*)g,
      (__attribute__((address_space(3))) unsigned int*)l, 16, 0, 0);
}

// ---------- prep: xb = bf16(x), xt = bf16(x + tokens[b]) ----------
__global__ void prep_x_kernel(const float* __restrict__ x, const float* __restrict__ tok,
                              bf16* __restrict__ xb, bf16* __restrict__ xt) {
  const size_t e = ((size_t)blockIdx.x * 256 + threadIdx.x) * 8;  // 4M elems total
  const int b = (int)(e >> 20);          // S*D = 1M per batch
  const int d = (int)(e & 1023);
  const float4 a0 = *(const float4*)(x + e);
  const float4 a1 = *(const float4*)(x + e + 4);
  const float4 t0 = *(const float4*)(tok + b * 1024 + d);
  const float4 t1 = *(const float4*)(tok + b * 1024 + d + 4);
  bf16x8 vb, vt;
  vb[0]=(bf16)a0.x; vb[1]=(bf16)a0.y; vb[2]=(bf16)a0.z; vb[3]=(bf16)a0.w;
  vb[4]=(bf16)a1.x; vb[5]=(bf16)a1.y; vb[6]=(bf16)a1.z; vb[7]=(bf16)a1.w;
  vt[0]=(bf16)(a0.x+t0.x); vt[1]=(bf16)(a0.y+t0.y); vt[2]=(bf16)(a0.z+t0.z); vt[3]=(bf16)(a0.w+t0.w);
  vt[4]=(bf16)(a1.x+t1.x); vt[5]=(bf16)(a1.y+t1.y); vt[6]=(bf16)(a1.z+t1.z); vt[7]=(bf16)(a1.w+t1.w);
  *(bf16x8*)(xb + e) = vb;
  *(bf16x8*)(xt + e) = vt;
}

// ---------- prep: Wq|Wk|Wv -> bf16 (contiguous 3M elems) ----------
__global__ void prep_w_kernel(const float* __restrict__ wq, const float* __restrict__ wk,
                              const float* __restrict__ wv, bf16* __restrict__ dst) {
  const size_t e = ((size_t)blockIdx.x * 256 + threadIdx.x) * 8;  // 3M elems
  const float* src; size_t off;
  if (e < (size_t)(1u<<20))      { src = wq; off = e; }
  else if (e < (size_t)(2u<<20)) { src = wk; off = e - (1u<<20); }
  else                           { src = wv; off = e - (2u<<20); }
  const float4 a0 = *(const float4*)(src + off);
  const float4 a1 = *(const float4*)(src + off + 4);
  bf16x8 v;
  v[0]=(bf16)a0.x; v[1]=(bf16)a0.y; v[2]=(bf16)a0.z; v[3]=(bf16)a0.w;
  v[4]=(bf16)a1.x; v[5]=(bf16)a1.y; v[6]=(bf16)a1.z; v[7]=(bf16)a1.w;
  *(bf16x8*)(dst + e) = v;
}

// ---------- QKV projection GEMM: C[m,n] = sum_k A[m,k]*B[n,k]  (m97 structure) ----------
// z=0: A=xt[4096,1024] B=Wq  -> cQ [B,H,S,hd] bf16, scaled by 1/8, bias 2*bq
// z=1: A=xt           B=Wk  -> cK [B,H,S,hd] bf16, bias 2*bk
// z=2: A=Wv[1024,1024] B=xb[4096,1024] -> Vt [B,H,hd,S] bf16 (V transposed), bias bv (along m)
__global__ __launch_bounds__(256) void qkv_gemm_kernel(
    const bf16* __restrict__ xt, const bf16* __restrict__ xb,
    const bf16* __restrict__ wq, const bf16* __restrict__ wk, const bf16* __restrict__ wv,
    const float* __restrict__ bq, const float* __restrict__ bk, const float* __restrict__ bv,
    bf16* __restrict__ cq, bf16* __restrict__ ck, bf16* __restrict__ vt)
{
  __shared__ __align__(16) char As[8192];   // 128 x 32 bf16
  __shared__ __align__(16) char Bs[8192];
  const int t = threadIdx.x, w = t >> 6, l = t & 63, g = l >> 4, c = l & 15;
  const int z = blockIdx.z;
  const bf16 *A, *B; const float* bias; bf16* outp;
  int tm, tn;
  if (z == 0)      { A = xt; B = wq; bias = bq; outp = cq; tm = blockIdx.x; tn = blockIdx.y; }
  else if (z == 1) { A = xt; B = wk; bias = bk; outp = ck; tm = blockIdx.x; tn = blockIdx.y; }
  else             { A = wv; B = xb; bias = bv; outp = vt; tm = blockIdx.y; tn = blockIdx.x; }
  const int m0 = tm * 128, n0 = tn * 128;
  const int wr = w >> 1, wc = w & 1;

  f32x4 acc[4][4] = {};
  const int arow  = w * 16 + (l >> 2);   // staging row (+64 for issue 1)
  const int acolb = (l & 3) * 16;        // byte within 64B row

  for (int k0 = 0; k0 < 1024; k0 += 32) {
    __syncthreads();
    const char* ag = (const char*)(A + (size_t)(m0 + arow) * 1024 + k0) + acolb;
    const char* bg = (const char*)(B + (size_t)(n0 + arow) * 1024 + k0) + acolb;
    gll16(ag,          As + w * 1024);
    gll16(ag + 131072, As + 4096 + w * 1024);   // +64 rows * 1024 elems * 2B
    gll16(bg,          Bs + w * 1024);
    gll16(bg + 131072, Bs + 4096 + w * 1024);
    __syncthreads();
    bf16x8 af[4], bfr[4];
#pragma unroll
    for (int mf = 0; mf < 4; ++mf)
      af[mf] = *(const bf16x8*)(As + (wr * 64 + mf * 16 + c) * 64 + g * 16);
#pragma unroll
    for (int nf = 0; nf < 4; ++nf)
      bfr[nf] = *(const bf16x8*)(Bs + (wc * 64 + nf * 16 + c) * 64 + g * 16);
#pragma unroll
    for (int mf = 0; mf < 4; ++mf)
#pragma unroll
      for (int nf = 0; nf < 4; ++nf)
        acc[mf][nf] = __builtin_amdgcn_mfma_f32_16x16x32_bf16(af[mf], bfr[nf], acc[mf][nf], 0, 0, 0);
  }

  // epilogue: D layout col=lane&15, row=(lane>>4)*4+r   [m89]
  if (z < 2) {
    const float sc = (z == 0) ? 0.125f : 1.0f;   // fold 1/sqrt(hd) into cQ
#pragma unroll
    for (int mf = 0; mf < 4; ++mf)
#pragma unroll
      for (int nf = 0; nf < 4; ++nf) {
        const int n = n0 + wc * 64 + nf * 16 + c;
        const int h = n >> 6, d = n & 63;
        const float bsum = 2.0f * bias[n];
#pragma unroll
        for (int r = 0; r < 4; ++r) {
          const int m = m0 + wr * 64 + mf * 16 + g * 4 + r;
          const int b = m >> 10, s = m & 1023;
          outp[(((size_t)(b * 16 + h)) * 1024 + s) * 64 + d] = (bf16)((acc[mf][nf][r] + bsum) * sc);
        }
      }
  } else {
#pragma unroll
    for (int mf = 0; mf < 4; ++mf)
#pragma unroll
      for (int nf = 0; nf < 4; ++nf) {
        const int n = n0 + wc * 64 + nf * 16 + c;   // x-row
        const int b = n >> 10, s = n & 1023;
#pragma unroll
        for (int r = 0; r < 4; ++r) {
          const int m = m0 + wr * 64 + mf * 16 + g * 4 + r;  // v-dim
          const int h = m >> 6, d = m & 63;
          outp[(((size_t)(b * 16 + h)) * 64 + d) * 1024 + s] = (bf16)(acc[mf][nf][r] + bias[m]);
        }
      }
  }
}

// ---------- flash attention ----------
// grid (16 qtiles, 64 bh), 256 threads = 4 waves, wave owns 16 q-rows.
// K tile [64 keys][64 d], Vt tile [64 d][64 keys], both XOR-swizzled (T2):
// LDS linear dest via global_load_lds + pre-swizzled global source (rule #21).
__global__ __launch_bounds__(256) void attn_kernel(
    const bf16* __restrict__ cq, const bf16* __restrict__ ck, const bf16* __restrict__ vt,
    float* __restrict__ out)
{
  __shared__ __align__(16) char Ks[8192];
  __shared__ __align__(16) char Vs[8192];
  __shared__ __align__(16) char Ps[8192];   // per-wave 16x64 bf16 P, swizzled
  const int t = threadIdx.x, w = t >> 6, l = t & 63, g = l >> 4, c = l & 15;
  const int bh = blockIdx.y, qt = blockIdx.x;
  const int b = bh >> 4, h = bh & 15;
  const bf16* cqb = cq + (size_t)bh * (1024 * 64);
  const bf16* ckb = ck + (size_t)bh * (1024 * 64);
  const bf16* vtb = vt + (size_t)bh * (64 * 1024);
  const int q0 = qt * 64 + w * 16;

  bf16x8 qf[2];
#pragma unroll
  for (int kf = 0; kf < 2; ++kf)
    qf[kf] = *(const bf16x8*)(cqb + (size_t)(q0 + c) * 64 + kf * 32 + g * 8);

  f32x4 o[4] = {};
  float mrow[4] = {-INFINITY, -INFINITY, -INFINITY, -INFINITY};
  float lrow[4] = {};

  const int srow = t >> 3;                    // staging row (+32 for issue 1)
  const int sch  = (t & 7) ^ (srow & 7);      // pre-swizzled chunk

  for (int t0 = 0; t0 < 1024; t0 += 64) {
    __syncthreads();
    {
      const char* kgb = (const char*)ckb + (size_t)t0 * 128;
      gll16(kgb + (size_t)srow * 128 + sch * 16,        Ks + w * 1024);
      gll16(kgb + (size_t)(srow + 32) * 128 + sch * 16, Ks + 4096 + w * 1024);
      const char* vgb = (const char*)vtb + (size_t)t0 * 2;
      gll16(vgb + (size_t)srow * 2048 + sch * 16,        Vs + w * 1024);
      gll16(vgb + (size_t)(srow + 32) * 2048 + sch * 16, Vs + 4096 + w * 1024);
    }
    __syncthreads();

    // S = cQ cK^T (scale already folded into cQ)
    f32x4 s[4] = {};
#pragma unroll
    for (int kf = 0; kf < 2; ++kf)
#pragma unroll
      for (int nf = 0; nf < 4; ++nf) {
        const int kr = nf * 16 + c;
        bf16x8 kb = *(const bf16x8*)(Ks + kr * 128 + (((kf * 4 + g) ^ (kr & 7)) << 4));
        s[nf] = __builtin_amdgcn_mfma_f32_16x16x32_bf16(qf[kf], kb, s[nf], 0, 0, 0);
      }

    // online softmax (fp32); rows r -> q0 + g*4 + r
#pragma unroll
    for (int r = 0; r < 4; ++r) {
      float vmax = fmaxf(fmaxf(s[0][r], s[1][r]), fmaxf(s[2][r], s[3][r]));
#pragma unroll
      for (int off = 1; off < 16; off <<= 1)
        vmax = fmaxf(vmax, __shfl_xor(vmax, off, 64));
      const float mnew = fmaxf(mrow[r], vmax);
      const float alpha = exp2f((mrow[r] - mnew) * LOG2E);
      mrow[r] = mnew;
      float ps = 0.f;
      const int prow = g * 4 + r;
#pragma unroll
      for (int nf = 0; nf < 4; ++nf) {
        const float p = exp2f((s[nf][r] - mnew) * LOG2E);
        ps += p;
        const int pcol = (nf * 32 + 2 * c) ^ ((prow & 7) << 4);
        *(bf16*)(Ps + w * 2048 + prow * 128 + pcol) = (bf16)p;
      }
#pragma unroll
      for (int off = 1; off < 16; off <<= 1)
        ps += __shfl_xor(ps, off, 64);
      lrow[r] = lrow[r] * alpha + ps;
#pragma unroll
      for (int nd = 0; nd < 4; ++nd) o[nd][r] *= alpha;
    }
    __syncthreads();   // cross-lane P visibility within wave (+ keeps waves phase-aligned)

    // O += P V : A = P (rows q), B = Vt (rows d, keys contiguous)
#pragma unroll
    for (int kf = 0; kf < 2; ++kf) {
      bf16x8 pa = *(const bf16x8*)(Ps + w * 2048 + c * 128 + (((kf * 4 + g) ^ (c & 7)) << 4));
#pragma unroll
      for (int nd = 0; nd < 4; ++nd) {
        const int vr = nd * 16 + c;
        bf16x8 vb = *(const bf16x8*)(Vs + vr * 128 + (((kf * 4 + g) ^ (vr & 7)) << 4));
        o[nd] = __builtin_amdgcn_mfma_f32_16x16x32_bf16(pa, vb, o[nd], 0, 0, 0);
      }
    }
  }

  // epilogue: out[b, s, h*64+d] fp32
#pragma unroll
  for (int r = 0; r < 4; ++r) {
    const int sq = q0 + g * 4 + r;
    const float inv = 1.0f / lrow[r];
    float* op = out + ((size_t)(b * 1024 + sq)) * 1024 + h * 64;
#pragma unroll
    for (int nd = 0; nd < 4; ++nd)
      op[nd * 16 + c] = o[nd][r] * inv;
  }
}

extern "C" void kernel_launch(void* const* d_in, const int* in_sizes, int n_in,
                              void* d_out, int out_size, void* d_ws, size_t ws_size,
                              hipStream_t stream) {
  const float* x   = (const float*)d_in[0];
  const float* tok = (const float*)d_in[1];
  const float* Wq  = (const float*)d_in[2];
  const float* bq  = (const float*)d_in[3];
  const float* Wk  = (const float*)d_in[4];
  const float* bk  = (const float*)d_in[5];
  const float* Wv  = (const float*)d_in[6];
  const float* bv  = (const float*)d_in[7];
  float* out = (float*)d_out;
  char* ws = (char*)d_ws;
  // workspace layout (46 MB total)
  bf16* xt  = (bf16*)(ws + (size_t)0);
  bf16* xb  = (bf16*)(ws + ((size_t)8  << 20));
  bf16* wqb = (bf16*)(ws + ((size_t)16 << 20));
  bf16* wkb = (bf16*)(ws + ((size_t)18 << 20));
  bf16* wvb = (bf16*)(ws + ((size_t)20 << 20));
  bf16* cqw = (bf16*)(ws + ((size_t)22 << 20));
  bf16* ckw = (bf16*)(ws + ((size_t)30 << 20));
  bf16* vtw = (bf16*)(ws + ((size_t)38 << 20));

  prep_x_kernel<<<dim3(2048), dim3(256), 0, stream>>>(x, tok, xb, xt);
  prep_w_kernel<<<dim3(1536), dim3(256), 0, stream>>>(Wq, Wk, Wv, wqb);
  qkv_gemm_kernel<<<dim3(32, 8, 3), dim3(256), 0, stream>>>(
      xt, xb, wqb, wkb, wvb, bq, bk, bv, cqw, ckw, vtw);
  attn_kernel<<<dim3(16, 64), dim3(256), 0, stream>>>(cqw, ckw, vtw, out);
}

// Round 2
// 101.229 us; speedup vs baseline: 1.2255x; 1.2255x over previous
//
#include <hip/hip_runtime.h>
#include <hip/hip_bf16.h>

// GuideAttentionModule: out = softmax((Q+tQ)(K+tK)^T/8) V, fused via
//   xt = x + tokens;  cQ = (xt@Wq.T + 2bq)*(0.125*log2e) ; cK = xt@Wk.T + 2bk ;
//   Vt = (x@Wv.T + bv)^T
// GEMMs: bf16 MFMA 16x16x32, fp32 acc. Attention: flash, swapped QK^T
// (S^T = mfma(K,Q)) so softmax is lane-local per q-column (4 shuffles/tile),
// log2-domain, double-buffered K/V staging (2-phase, 1 barrier/tile),
// O^T accumulation + LDS transpose epilogue.

typedef __bf16 bf16;
typedef __bf16 bf16x4 __attribute__((ext_vector_type(4)));
typedef __bf16 bf16x8 __attribute__((ext_vector_type(8)));
typedef float  f32x4  __attribute__((ext_vector_type(4)));

#define LOG2E 1.4426950408889634f

__device__ __forceinline__ void gll16(const void* g, void* l) {
  __builtin_amdgcn_global_load_lds(
      (const __attribute__((address_space(1))) unsigned int*)g,
      (__attribute__((address_space(3))) unsigned int*)l, 16, 0, 0);
}

// ---------- prep: xb = bf16(x), xt = bf16(x + tokens[b]) ----------
__global__ void prep_x_kernel(const float* __restrict__ x, const float* __restrict__ tok,
                              bf16* __restrict__ xb, bf16* __restrict__ xt) {
  const size_t e = ((size_t)blockIdx.x * 256 + threadIdx.x) * 8;  // 4M elems total
  const int b = (int)(e >> 20);          // S*D = 1M per batch
  const int d = (int)(e & 1023);
  const float4 a0 = *(const float4*)(x + e);
  const float4 a1 = *(const float4*)(x + e + 4);
  const float4 t0 = *(const float4*)(tok + b * 1024 + d);
  const float4 t1 = *(const float4*)(tok + b * 1024 + d + 4);
  bf16x8 vb, vt;
  vb[0]=(bf16)a0.x; vb[1]=(bf16)a0.y; vb[2]=(bf16)a0.z; vb[3]=(bf16)a0.w;
  vb[4]=(bf16)a1.x; vb[5]=(bf16)a1.y; vb[6]=(bf16)a1.z; vb[7]=(bf16)a1.w;
  vt[0]=(bf16)(a0.x+t0.x); vt[1]=(bf16)(a0.y+t0.y); vt[2]=(bf16)(a0.z+t0.z); vt[3]=(bf16)(a0.w+t0.w);
  vt[4]=(bf16)(a1.x+t1.x); vt[5]=(bf16)(a1.y+t1.y); vt[6]=(bf16)(a1.z+t1.z); vt[7]=(bf16)(a1.w+t1.w);
  *(bf16x8*)(xb + e) = vb;
  *(bf16x8*)(xt + e) = vt;
}

// ---------- prep: Wq|Wk|Wv -> bf16 (contiguous 3M elems) ----------
__global__ void prep_w_kernel(const float* __restrict__ wq, const float* __restrict__ wk,
                              const float* __restrict__ wv, bf16* __restrict__ dst) {
  const size_t e = ((size_t)blockIdx.x * 256 + threadIdx.x) * 8;  // 3M elems
  const float* src; size_t off;
  if (e < (size_t)(1u<<20))      { src = wq; off = e; }
  else if (e < (size_t)(2u<<20)) { src = wk; off = e - (1u<<20); }
  else                           { src = wv; off = e - (2u<<20); }
  const float4 a0 = *(const float4*)(src + off);
  const float4 a1 = *(const float4*)(src + off + 4);
  bf16x8 v;
  v[0]=(bf16)a0.x; v[1]=(bf16)a0.y; v[2]=(bf16)a0.z; v[3]=(bf16)a0.w;
  v[4]=(bf16)a1.x; v[5]=(bf16)a1.y; v[6]=(bf16)a1.z; v[7]=(bf16)a1.w;
  *(bf16x8*)(dst + e) = v;
}

// ---------- QKV projection GEMM: C[m,n] = sum_k A[m,k]*B[n,k]  (m97 structure) ----------
// z=0: A=xt[4096,1024] B=Wq -> cQ [B,H,S,hd] bf16, scaled 0.125*log2e, bias 2*bq
// z=1: A=xt            B=Wk -> cK [B,H,S,hd] bf16, bias 2*bk
// z=2: A=Wv[1024,1024] B=xb[4096,1024] -> Vt [B,H,hd,S] bf16 (V transposed), bias bv (along m)
__global__ __launch_bounds__(256) void qkv_gemm_kernel(
    const bf16* __restrict__ xt, const bf16* __restrict__ xb,
    const bf16* __restrict__ wq, const bf16* __restrict__ wk, const bf16* __restrict__ wv,
    const float* __restrict__ bq, const float* __restrict__ bk, const float* __restrict__ bv,
    bf16* __restrict__ cq, bf16* __restrict__ ck, bf16* __restrict__ vt)
{
  __shared__ __align__(16) char As[8192];   // 128 x 32 bf16
  __shared__ __align__(16) char Bs[8192];
  const int t = threadIdx.x, w = t >> 6, l = t & 63, g = l >> 4, c = l & 15;
  const int z = blockIdx.z;
  const bf16 *A, *B; const float* bias; bf16* outp;
  int tm, tn;
  if (z == 0)      { A = xt; B = wq; bias = bq; outp = cq; tm = blockIdx.x; tn = blockIdx.y; }
  else if (z == 1) { A = xt; B = wk; bias = bk; outp = ck; tm = blockIdx.x; tn = blockIdx.y; }
  else             { A = wv; B = xb; bias = bv; outp = vt; tm = blockIdx.y; tn = blockIdx.x; }
  const int m0 = tm * 128, n0 = tn * 128;
  const int wr = w >> 1, wc = w & 1;

  f32x4 acc[4][4] = {};
  const int arow  = w * 16 + (l >> 2);   // staging row (+64 for issue 1)
  const int acolb = (l & 3) * 16;        // byte within 64B row

  for (int k0 = 0; k0 < 1024; k0 += 32) {
    __syncthreads();
    const char* ag = (const char*)(A + (size_t)(m0 + arow) * 1024 + k0) + acolb;
    const char* bg = (const char*)(B + (size_t)(n0 + arow) * 1024 + k0) + acolb;
    gll16(ag,          As + w * 1024);
    gll16(ag + 131072, As + 4096 + w * 1024);   // +64 rows * 1024 elems * 2B
    gll16(bg,          Bs + w * 1024);
    gll16(bg + 131072, Bs + 4096 + w * 1024);
    __syncthreads();
    bf16x8 af[4], bfr[4];
#pragma unroll
    for (int mf = 0; mf < 4; ++mf)
      af[mf] = *(const bf16x8*)(As + (wr * 64 + mf * 16 + c) * 64 + g * 16);
#pragma unroll
    for (int nf = 0; nf < 4; ++nf)
      bfr[nf] = *(const bf16x8*)(Bs + (wc * 64 + nf * 16 + c) * 64 + g * 16);
#pragma unroll
    for (int mf = 0; mf < 4; ++mf)
#pragma unroll
      for (int nf = 0; nf < 4; ++nf)
        acc[mf][nf] = __builtin_amdgcn_mfma_f32_16x16x32_bf16(af[mf], bfr[nf], acc[mf][nf], 0, 0, 0);
  }

  // epilogue: D layout col=lane&15, row=(lane>>4)*4+r   [m89]
  if (z < 2) {
    const float sc = (z == 0) ? 0.125f * LOG2E : 1.0f;  // fold 1/sqrt(hd) and log2e into cQ
#pragma unroll
    for (int mf = 0; mf < 4; ++mf)
#pragma unroll
      for (int nf = 0; nf < 4; ++nf) {
        const int n = n0 + wc * 64 + nf * 16 + c;
        const int h = n >> 6, d = n & 63;
        const float bsum = 2.0f * bias[n];
#pragma unroll
        for (int r = 0; r < 4; ++r) {
          const int m = m0 + wr * 64 + mf * 16 + g * 4 + r;
          const int b = m >> 10, s = m & 1023;
          outp[(((size_t)(b * 16 + h)) * 1024 + s) * 64 + d] = (bf16)((acc[mf][nf][r] + bsum) * sc);
        }
      }
  } else {
#pragma unroll
    for (int mf = 0; mf < 4; ++mf)
#pragma unroll
      for (int nf = 0; nf < 4; ++nf) {
        const int n = n0 + wc * 64 + nf * 16 + c;   // x-row
        const int b = n >> 10, s = n & 1023;
#pragma unroll
        for (int r = 0; r < 4; ++r) {
          const int m = m0 + wr * 64 + mf * 16 + g * 4 + r;  // v-dim
          const int h = m >> 6, d = m & 63;
          outp[(((size_t)(b * 16 + h)) * 64 + d) * 1024 + s] = (bf16)(acc[mf][nf][r] + bias[m]);
        }
      }
  }
}

// ---------- flash attention (swapped QK^T, 2-phase dbuf) ----------
// grid (16 qtiles, 64 bh), 256 threads = 4 waves, wave owns 16 q-rows.
// LDS: K dbuf 2x8KB | V dbuf 2x8KB | P 8KB (per-wave 2KB). K/V tiles staged
// via global_load_lds with pre-swizzled global source (rule #21), XOR chunk
// swizzle ^ (row&7) on 16B chunks.
__global__ __launch_bounds__(256) void attn_kernel(
    const bf16* __restrict__ cq, const bf16* __restrict__ ck, const bf16* __restrict__ vt,
    float* __restrict__ out)
{
  __shared__ __align__(16) char LDS[40960];
  const int t = threadIdx.x, w = t >> 6, l = t & 63, g = l >> 4, c = l & 15;
  const int bh = blockIdx.y, qt = blockIdx.x;
  const int b = bh >> 4, h = bh & 15;
  const bf16* cqb = cq + (size_t)bh * 65536;
  const bf16* ckb = ck + (size_t)bh * 65536;
  const bf16* vtb = vt + (size_t)bh * 65536;
  const int q0 = qt * 64 + w * 16;
  char* Ps = LDS + 32768 + w * 2048;

  // Q as B-fragment: lane (g,c) holds cQ[q0+c][kf*32 + g*8 + j]
  bf16x8 qf[2];
#pragma unroll
  for (int kf = 0; kf < 2; ++kf)
    qf[kf] = *(const bf16x8*)(cqb + (size_t)(q0 + c) * 64 + kf * 32 + g * 8);

  f32x4 o[4] = {};                       // O^T: o[nd][r] = O[q=c][d=nd*16+g*4+r]
  float m = -INFINITY, lsum = 0.f;       // per q=c (replicated across g)

  const int srow = t >> 3;               // staging row 0..31
  const int sch  = (t & 7) ^ (srow & 7); // pre-swizzled 16B chunk
  const size_t ksrc = (size_t)srow * 128  + (size_t)sch * 16;
  const size_t vsrc = (size_t)srow * 2048 + (size_t)sch * 16;

#define STAGE(buf, t0)                                                   \
  {                                                                      \
    const char* kgb = (const char*)ckb + (size_t)(t0) * 128;             \
    const char* vgb = (const char*)vtb + (size_t)(t0) * 2;               \
    char* kd = LDS + (buf) * 8192 + w * 1024;                            \
    char* vd = LDS + 16384 + (buf) * 8192 + w * 1024;                    \
    gll16(kgb + ksrc,         kd);                                       \
    gll16(kgb + 4096 + ksrc,  kd + 4096);  /* rows 32..63 */             \
    gll16(vgb + vsrc,         vd);                                       \
    gll16(vgb + 65536 + vsrc, vd + 4096);  /* d-rows 32..63 */           \
  }

  STAGE(0, 0);
  __syncthreads();
  int buf = 0;

  for (int t0 = 0; t0 < 1024; t0 += 64) {
    if (t0 + 64 < 1024) STAGE(buf ^ 1, t0 + 64);
    const char* Kb = LDS + buf * 8192;
    const char* Vb = LDS + 16384 + buf * 8192;

    // S^T = K·Q^T : s[nf][r] = S[key=nf*16+g*4+r][q=c]  (log2 units)
    f32x4 s[4] = {};
#pragma unroll
    for (int kf = 0; kf < 2; ++kf)
#pragma unroll
      for (int nf = 0; nf < 4; ++nf) {
        const int kr = nf * 16 + c;
        bf16x8 kb = *(const bf16x8*)(Kb + kr * 128 + (((kf * 4 + g) ^ (kr & 7)) << 4));
        s[nf] = __builtin_amdgcn_mfma_f32_16x16x32_bf16(kb, qf[kf], s[nf], 0, 0, 0);
      }

    // lane-local softmax for q=c: 16 own scores + 2 shuffles per reduce
    float vmax = s[0][0];
#pragma unroll
    for (int nf = 0; nf < 4; ++nf)
#pragma unroll
      for (int r = 0; r < 4; ++r) vmax = fmaxf(vmax, s[nf][r]);
    vmax = fmaxf(vmax, __shfl_xor(vmax, 16, 64));
    vmax = fmaxf(vmax, __shfl_xor(vmax, 32, 64));
    const float mnew = fmaxf(m, vmax);
    const float alpha = exp2f(m - mnew);
    m = mnew;

    float p[4][4];
    float ps = 0.f;
#pragma unroll
    for (int nf = 0; nf < 4; ++nf)
#pragma unroll
      for (int r = 0; r < 4; ++r) {
        p[nf][r] = exp2f(s[nf][r] - mnew);
        ps += p[nf][r];
      }
    // pack P -> LDS (wave-private, swizzled): row q=c, keys nf*16+g*4..+3
#pragma unroll
    for (int nf = 0; nf < 4; ++nf) {
      bf16x4 pw;
      pw[0] = (bf16)p[nf][0]; pw[1] = (bf16)p[nf][1];
      pw[2] = (bf16)p[nf][2]; pw[3] = (bf16)p[nf][3];
      // data chunk nf*2 + g/2, 8B half g&1 -> express as byte addr then XOR on chunk bits
      const int byteoff = (nf * 32 + g * 8) ^ ((c & 7) << 4);
      *(bf16x4*)(Ps + c * 128 + byteoff) = pw;
    }
    ps += __shfl_xor(ps, 16, 64);
    ps += __shfl_xor(ps, 32, 64);
    lsum = lsum * alpha + ps;
#pragma unroll
    for (int nd = 0; nd < 4; ++nd) o[nd] *= alpha;

    // O^T += Vt·P^T : A = Vt rows d, B = P^T (lane (g,c): P[q=c][kf*32+g*8+j])
    bf16x8 pa[2];
#pragma unroll
    for (int kf = 0; kf < 2; ++kf)
      pa[kf] = *(const bf16x8*)(Ps + c * 128 + (((kf * 4 + g) ^ (c & 7)) << 4));
#pragma unroll
    for (int kf = 0; kf < 2; ++kf)
#pragma unroll
      for (int nd = 0; nd < 4; ++nd) {
        const int vr = nd * 16 + c;
        bf16x8 vb = *(const bf16x8*)(Vb + vr * 128 + (((kf * 4 + g) ^ (vr & 7)) << 4));
        o[nd] = __builtin_amdgcn_mfma_f32_16x16x32_bf16(vb, pa[kf], o[nd], 0, 0, 0);
      }

    __syncthreads();   // staged buf^1 landed (vmcnt drain) + all waves done with buf
    buf ^= 1;
  }

#undef STAGE

  // epilogue: transpose O^T through LDS (reuse K region, 64x64 fp32, swizzled)
  const float inv = 1.0f / lsum;
  {
    char* Ob = LDS;  // [64 rows q][16 chunks of 16B]
    const int row = w * 16 + c;
#pragma unroll
    for (int nd = 0; nd < 4; ++nd) {
      f32x4 vo = o[nd] * inv;
      const int pch = (nd * 4 + g) ^ (row & 7);   // physical chunk
      *(f32x4*)(Ob + row * 256 + (pch << 4)) = vo;
    }
  }
  __syncthreads();
  {
    const int rr = t >> 2;                 // output row 0..63
    float* orow = out + ((size_t)(b * 1024 + qt * 64 + rr)) * 1024 + h * 64;
#pragma unroll
    for (int i = 0; i < 4; ++i) {
      const int ch = (t & 3) + i * 4;      // data chunk = d/4
      f32x4 v = *(const f32x4*)(LDS + rr * 256 + ((ch ^ (rr & 7)) << 4));
      *(f32x4*)(orow + ch * 4) = v;
    }
  }
}

extern "C" void kernel_launch(void* const* d_in, const int* in_sizes, int n_in,
                              void* d_out, int out_size, void* d_ws, size_t ws_size,
                              hipStream_t stream) {
  const float* x   = (const float*)d_in[0];
  const float* tok = (const float*)d_in[1];
  const float* Wq  = (const float*)d_in[2];
  const float* bq  = (const float*)d_in[3];
  const float* Wk  = (const float*)d_in[4];
  const float* bk  = (const float*)d_in[5];
  const float* Wv  = (const float*)d_in[6];
  const float* bv  = (const float*)d_in[7];
  float* out = (float*)d_out;
  char* ws = (char*)d_ws;
  // workspace layout (46 MB total)
  bf16* xt  = (bf16*)(ws + (size_t)0);
  bf16* xb  = (bf16*)(ws + ((size_t)8  << 20));
  bf16* wqb = (bf16*)(ws + ((size_t)16 << 20));
  bf16* wkb = (bf16*)(ws + ((size_t)18 << 20));
  bf16* wvb = (bf16*)(ws + ((size_t)20 << 20));
  bf16* cqw = (bf16*)(ws + ((size_t)22 << 20));
  bf16* ckw = (bf16*)(ws + ((size_t)30 << 20));
  bf16* vtw = (bf16*)(ws + ((size_t)38 << 20));

  prep_x_kernel<<<dim3(2048), dim3(256), 0, stream>>>(x, tok, xb, xt);
  prep_w_kernel<<<dim3(1536), dim3(256), 0, stream>>>(Wq, Wk, Wv, wqb);
  qkv_gemm_kernel<<<dim3(32, 8, 3), dim3(256), 0, stream>>>(
      xt, xb, wqb, wkb, wvb, bq, bk, bv, cqw, ckw, vtw);
  attn_kernel<<<dim3(16, 64), dim3(256), 0, stream>>>(cqw, ckw, vtw, out);
}

// Round 3
// 98.382 us; speedup vs baseline: 1.2610x; 1.0289x over previous
//
#include <hip/hip_runtime.h>
#include <hip/hip_bf16.h>

// GuideAttentionModule: out = softmax((Q+tQ)(K+tK)^T/8) V, fused via
//   xt = x + tokens;  cQ = (xt@Wq.T + 2bq)*(0.125*log2e) ; cK = xt@Wk.T + 2bk ;
//   Vt = (x@Wv.T + bv)^T
// GEMMs: bf16 MFMA 16x16x32, fp32 acc, BK=64, 128B-row XOR-swizzled LDS
// (conflict-free ds_read_b128), XCD-aware block remap for L2 panel locality.
// Attention: flash, swapped QK^T (S^T = mfma(K,Q)), lane-local softmax,
// log2-domain, double-buffered K/V staging, O^T + LDS transpose epilogue.

typedef __bf16 bf16;
typedef __bf16 bf16x4 __attribute__((ext_vector_type(4)));
typedef __bf16 bf16x8 __attribute__((ext_vector_type(8)));
typedef float  f32x4  __attribute__((ext_vector_type(4)));

#define LOG2E 1.4426950408889634f

__device__ __forceinline__ void gll16(const void* g, void* l) {
  __builtin_amdgcn_global_load_lds(
      (const __attribute__((address_space(1))) unsigned int*)g,
      (__attribute__((address_space(3))) unsigned int*)l, 16, 0, 0);
}

// ---------- prep: xb = bf16(x), xt = bf16(x + tokens[b]) ----------
__global__ void prep_x_kernel(const float* __restrict__ x, const float* __restrict__ tok,
                              bf16* __restrict__ xb, bf16* __restrict__ xt) {
  const size_t e = ((size_t)blockIdx.x * 256 + threadIdx.x) * 8;  // 4M elems total
  const int b = (int)(e >> 20);          // S*D = 1M per batch
  const int d = (int)(e & 1023);
  const float4 a0 = *(const float4*)(x + e);
  const float4 a1 = *(const float4*)(x + e + 4);
  const float4 t0 = *(const float4*)(tok + b * 1024 + d);
  const float4 t1 = *(const float4*)(tok + b * 1024 + d + 4);
  bf16x8 vb, vt;
  vb[0]=(bf16)a0.x; vb[1]=(bf16)a0.y; vb[2]=(bf16)a0.z; vb[3]=(bf16)a0.w;
  vb[4]=(bf16)a1.x; vb[5]=(bf16)a1.y; vb[6]=(bf16)a1.z; vb[7]=(bf16)a1.w;
  vt[0]=(bf16)(a0.x+t0.x); vt[1]=(bf16)(a0.y+t0.y); vt[2]=(bf16)(a0.z+t0.z); vt[3]=(bf16)(a0.w+t0.w);
  vt[4]=(bf16)(a1.x+t1.x); vt[5]=(bf16)(a1.y+t1.y); vt[6]=(bf16)(a1.z+t1.z); vt[7]=(bf16)(a1.w+t1.w);
  *(bf16x8*)(xb + e) = vb;
  *(bf16x8*)(xt + e) = vt;
}

// ---------- prep: Wq|Wk|Wv -> bf16 (contiguous 3M elems) ----------
__global__ void prep_w_kernel(const float* __restrict__ wq, const float* __restrict__ wk,
                              const float* __restrict__ wv, bf16* __restrict__ dst) {
  const size_t e = ((size_t)blockIdx.x * 256 + threadIdx.x) * 8;  // 3M elems
  const float* src; size_t off;
  if (e < (size_t)(1u<<20))      { src = wq; off = e; }
  else if (e < (size_t)(2u<<20)) { src = wk; off = e - (1u<<20); }
  else                           { src = wv; off = e - (2u<<20); }
  const float4 a0 = *(const float4*)(src + off);
  const float4 a1 = *(const float4*)(src + off + 4);
  bf16x8 v;
  v[0]=(bf16)a0.x; v[1]=(bf16)a0.y; v[2]=(bf16)a0.z; v[3]=(bf16)a0.w;
  v[4]=(bf16)a1.x; v[5]=(bf16)a1.y; v[6]=(bf16)a1.z; v[7]=(bf16)a1.w;
  *(bf16x8*)(dst + e) = v;
}

// ---------- QKV projection GEMM: C[m,n] = sum_k A[m,k]*B[n,k] ----------
// BK=64, 128B LDS rows, chunk ^ (row&7) swizzle, conflict-free ds_read_b128.
// z=0: A=xt[4096,1024] B=Wq -> cQ [B,H,S,hd] bf16, scaled 0.125*log2e, bias 2*bq
// z=1: A=xt            B=Wk -> cK [B,H,S,hd] bf16, bias 2*bk
// z=2: A=Wv[1024,1024] B=xb[4096,1024] -> Vt [B,H,hd,S] bf16, bias bv (along m)
__global__ __launch_bounds__(256) void qkv_gemm_kernel(
    const bf16* __restrict__ xt, const bf16* __restrict__ xb,
    const bf16* __restrict__ wq, const bf16* __restrict__ wk, const bf16* __restrict__ wv,
    const float* __restrict__ bq, const float* __restrict__ bk, const float* __restrict__ bv,
    bf16* __restrict__ cq, bf16* __restrict__ ck, bf16* __restrict__ vt)
{
  __shared__ __align__(16) char As[16384];   // 128 rows x 128B (BK=64 bf16)
  __shared__ __align__(16) char Bs[16384];
  const int t = threadIdx.x, w = t >> 6, l = t & 63, g = l >> 4, c = l & 15;
  const int z = blockIdx.z;
  // XCD-aware remap: xcd = bx&7; each XCD gets 4 contiguous m-tiles x all 8
  // n-tiles -> per-XCD panel working set ~3MB < 4MB L2 (T1, m192).
  const int bx = blockIdx.x, by = blockIdx.y;
  const int f = bx & 7, s2 = (bx >> 3) + 4 * by;   // s2: 0..31
  const int tmx = f * 4 + (s2 & 3);                // 0..31
  const int tny = s2 >> 2;                         // 0..7
  const bf16 *A, *B; const float* bias; bf16* outp;
  int tm, tn;
  if (z == 0)      { A = xt; B = wq; bias = bq; outp = cq; tm = tmx; tn = tny; }
  else if (z == 1) { A = xt; B = wk; bias = bk; outp = ck; tm = tmx; tn = tny; }
  else             { A = wv; B = xb; bias = bv; outp = vt; tm = tny; tn = tmx; }
  const int m0 = tm * 128, n0 = tn * 128;
  const int wr = w >> 1, wc = w & 1;

  f32x4 acc[4][4] = {};
  // staging: thread t writes LDS linear (round*4096 + t*16); LDS(row, pchunk)
  // holds global (row, kchunk = pchunk ^ (row&7)). row = round*32 + (t>>3).
  const int lr0 = t >> 3, pc = t & 7;
  const size_t ssw = (size_t)lr0 * 2048 + (size_t)((pc ^ (lr0 & 7)) << 4);

  for (int k0 = 0; k0 < 1024; k0 += 64) {
    __syncthreads();
    const char* ag = (const char*)A + (size_t)m0 * 2048 + (size_t)k0 * 2 + ssw;
    const char* bg = (const char*)B + (size_t)n0 * 2048 + (size_t)k0 * 2 + ssw;
#pragma unroll
    for (int i = 0; i < 4; ++i) {
      gll16(ag + i * 65536, As + i * 4096 + w * 1024);   // +32 rows * 2048B
      gll16(bg + i * 65536, Bs + i * 4096 + w * 1024);
    }
    __syncthreads();
#pragma unroll
    for (int kf = 0; kf < 2; ++kf) {
      bf16x8 af[4], bfr[4];
#pragma unroll
      for (int mf = 0; mf < 4; ++mf) {
        const int row = wr * 64 + mf * 16 + c;
        af[mf] = *(const bf16x8*)(As + row * 128 + (((kf * 4 + g) ^ (row & 7)) << 4));
      }
#pragma unroll
      for (int nf = 0; nf < 4; ++nf) {
        const int row = wc * 64 + nf * 16 + c;
        bfr[nf] = *(const bf16x8*)(Bs + row * 128 + (((kf * 4 + g) ^ (row & 7)) << 4));
      }
#pragma unroll
      for (int mf = 0; mf < 4; ++mf)
#pragma unroll
        for (int nf = 0; nf < 4; ++nf)
          acc[mf][nf] = __builtin_amdgcn_mfma_f32_16x16x32_bf16(af[mf], bfr[nf], acc[mf][nf], 0, 0, 0);
    }
  }

  // epilogue: D layout col=lane&15, row=(lane>>4)*4+r   [m89]
  if (z < 2) {
    const float sc = (z == 0) ? 0.125f * LOG2E : 1.0f;  // fold 1/sqrt(hd), log2e into cQ
#pragma unroll
    for (int mf = 0; mf < 4; ++mf)
#pragma unroll
      for (int nf = 0; nf < 4; ++nf) {
        const int n = n0 + wc * 64 + nf * 16 + c;
        const int h = n >> 6, d = n & 63;
        const float bsum = 2.0f * bias[n];
#pragma unroll
        for (int r = 0; r < 4; ++r) {
          const int m = m0 + wr * 64 + mf * 16 + g * 4 + r;
          const int b = m >> 10, s = m & 1023;
          outp[(((size_t)(b * 16 + h)) * 1024 + s) * 64 + d] = (bf16)((acc[mf][nf][r] + bsum) * sc);
        }
      }
  } else {
#pragma unroll
    for (int mf = 0; mf < 4; ++mf)
#pragma unroll
      for (int nf = 0; nf < 4; ++nf) {
        const int n = n0 + wc * 64 + nf * 16 + c;   // x-row
        const int b = n >> 10, s = n & 1023;
#pragma unroll
        for (int r = 0; r < 4; ++r) {
          const int m = m0 + wr * 64 + mf * 16 + g * 4 + r;  // v-dim
          const int h = m >> 6, d = m & 63;
          outp[(((size_t)(b * 16 + h)) * 64 + d) * 1024 + s] = (bf16)(acc[mf][nf][r] + bias[m]);
        }
      }
  }
}

// ---------- flash attention (swapped QK^T, 2-phase dbuf) ----------
__global__ __launch_bounds__(256) void attn_kernel(
    const bf16* __restrict__ cq, const bf16* __restrict__ ck, const bf16* __restrict__ vt,
    float* __restrict__ out)
{
  __shared__ __align__(16) char LDS[40960];
  const int t = threadIdx.x, w = t >> 6, l = t & 63, g = l >> 4, c = l & 15;
  const int bh = blockIdx.y, qt = blockIdx.x;
  const int b = bh >> 4, h = bh & 15;
  const bf16* cqb = cq + (size_t)bh * 65536;
  const bf16* ckb = ck + (size_t)bh * 65536;
  const bf16* vtb = vt + (size_t)bh * 65536;
  const int q0 = qt * 64 + w * 16;
  char* Ps = LDS + 32768 + w * 2048;

  // Q as B-fragment: lane (g,c) holds cQ[q0+c][kf*32 + g*8 + j]
  bf16x8 qf[2];
#pragma unroll
  for (int kf = 0; kf < 2; ++kf)
    qf[kf] = *(const bf16x8*)(cqb + (size_t)(q0 + c) * 64 + kf * 32 + g * 8);

  f32x4 o[4] = {};                       // O^T: o[nd][r] = O[q=c][d=nd*16+g*4+r]
  float m = -INFINITY, lsum = 0.f;       // per q=c (replicated across g)

  const int srow = t >> 3;               // staging row 0..31
  const int sch  = (t & 7) ^ (srow & 7); // pre-swizzled 16B chunk
  const size_t ksrc = (size_t)srow * 128  + (size_t)sch * 16;
  const size_t vsrc = (size_t)srow * 2048 + (size_t)sch * 16;

#define STAGE(buf, t0)                                                   \
  {                                                                      \
    const char* kgb = (const char*)ckb + (size_t)(t0) * 128;             \
    const char* vgb = (const char*)vtb + (size_t)(t0) * 2;               \
    char* kd = LDS + (buf) * 8192 + w * 1024;                            \
    char* vd = LDS + 16384 + (buf) * 8192 + w * 1024;                    \
    gll16(kgb + ksrc,         kd);                                       \
    gll16(kgb + 4096 + ksrc,  kd + 4096);  /* rows 32..63 */             \
    gll16(vgb + vsrc,         vd);                                       \
    gll16(vgb + 65536 + vsrc, vd + 4096);  /* d-rows 32..63 */           \
  }

  STAGE(0, 0);
  __syncthreads();
  int buf = 0;

  for (int t0 = 0; t0 < 1024; t0 += 64) {
    if (t0 + 64 < 1024) STAGE(buf ^ 1, t0 + 64);
    const char* Kb = LDS + buf * 8192;
    const char* Vb = LDS + 16384 + buf * 8192;

    // S^T = K·Q^T : s[nf][r] = S[key=nf*16+g*4+r][q=c]  (log2 units)
    f32x4 s[4] = {};
#pragma unroll
    for (int kf = 0; kf < 2; ++kf)
#pragma unroll
      for (int nf = 0; nf < 4; ++nf) {
        const int kr = nf * 16 + c;
        bf16x8 kb = *(const bf16x8*)(Kb + kr * 128 + (((kf * 4 + g) ^ (kr & 7)) << 4));
        s[nf] = __builtin_amdgcn_mfma_f32_16x16x32_bf16(kb, qf[kf], s[nf], 0, 0, 0);
      }

    // lane-local softmax for q=c: 16 own scores + 2 shuffles per reduce
    float vmax = s[0][0];
#pragma unroll
    for (int nf = 0; nf < 4; ++nf)
#pragma unroll
      for (int r = 0; r < 4; ++r) vmax = fmaxf(vmax, s[nf][r]);
    vmax = fmaxf(vmax, __shfl_xor(vmax, 16, 64));
    vmax = fmaxf(vmax, __shfl_xor(vmax, 32, 64));
    const float mnew = fmaxf(m, vmax);
    const float alpha = exp2f(m - mnew);
    m = mnew;

    float p[4][4];
    float ps = 0.f;
#pragma unroll
    for (int nf = 0; nf < 4; ++nf)
#pragma unroll
      for (int r = 0; r < 4; ++r) {
        p[nf][r] = exp2f(s[nf][r] - mnew);
        ps += p[nf][r];
      }
    // pack P -> LDS (wave-private, swizzled): row q=c, keys nf*16+g*4..+3
#pragma unroll
    for (int nf = 0; nf < 4; ++nf) {
      bf16x4 pw;
      pw[0] = (bf16)p[nf][0]; pw[1] = (bf16)p[nf][1];
      pw[2] = (bf16)p[nf][2]; pw[3] = (bf16)p[nf][3];
      const int byteoff = (nf * 32 + g * 8) ^ ((c & 7) << 4);
      *(bf16x4*)(Ps + c * 128 + byteoff) = pw;
    }
    ps += __shfl_xor(ps, 16, 64);
    ps += __shfl_xor(ps, 32, 64);
    lsum = lsum * alpha + ps;
#pragma unroll
    for (int nd = 0; nd < 4; ++nd) o[nd] *= alpha;

    // O^T += Vt·P^T : A = Vt rows d, B = P^T (lane (g,c): P[q=c][kf*32+g*8+j])
    bf16x8 pa[2];
#pragma unroll
    for (int kf = 0; kf < 2; ++kf)
      pa[kf] = *(const bf16x8*)(Ps + c * 128 + (((kf * 4 + g) ^ (c & 7)) << 4));
#pragma unroll
    for (int kf = 0; kf < 2; ++kf)
#pragma unroll
      for (int nd = 0; nd < 4; ++nd) {
        const int vr = nd * 16 + c;
        bf16x8 vb = *(const bf16x8*)(Vb + vr * 128 + (((kf * 4 + g) ^ (vr & 7)) << 4));
        o[nd] = __builtin_amdgcn_mfma_f32_16x16x32_bf16(vb, pa[kf], o[nd], 0, 0, 0);
      }

    __syncthreads();   // staged buf^1 landed (vmcnt drain) + all waves done with buf
    buf ^= 1;
  }

#undef STAGE

  // epilogue: transpose O^T through LDS (reuse K region, 64x64 fp32, swizzled)
  const float inv = 1.0f / lsum;
  {
    char* Ob = LDS;  // [64 rows q][16 chunks of 16B]
    const int row = w * 16 + c;
#pragma unroll
    for (int nd = 0; nd < 4; ++nd) {
      f32x4 vo = o[nd] * inv;
      const int pch = (nd * 4 + g) ^ (row & 7);   // physical chunk
      *(f32x4*)(Ob + row * 256 + (pch << 4)) = vo;
    }
  }
  __syncthreads();
  {
    const int rr = t >> 2;                 // output row 0..63
    float* orow = out + ((size_t)(b * 1024 + qt * 64 + rr)) * 1024 + h * 64;
#pragma unroll
    for (int i = 0; i < 4; ++i) {
      const int ch = (t & 3) + i * 4;      // data chunk = d/4
      f32x4 v = *(const f32x4*)(LDS + rr * 256 + ((ch ^ (rr & 7)) << 4));
      *(f32x4*)(orow + ch * 4) = v;
    }
  }
}

extern "C" void kernel_launch(void* const* d_in, const int* in_sizes, int n_in,
                              void* d_out, int out_size, void* d_ws, size_t ws_size,
                              hipStream_t stream) {
  const float* x   = (const float*)d_in[0];
  const float* tok = (const float*)d_in[1];
  const float* Wq  = (const float*)d_in[2];
  const float* bq  = (const float*)d_in[3];
  const float* Wk  = (const float*)d_in[4];
  const float* bk  = (const float*)d_in[5];
  const float* Wv  = (const float*)d_in[6];
  const float* bv  = (const float*)d_in[7];
  float* out = (float*)d_out;
  char* ws = (char*)d_ws;
  // workspace layout (46 MB total)
  bf16* xt  = (bf16*)(ws + (size_t)0);
  bf16* xb  = (bf16*)(ws + ((size_t)8  << 20));
  bf16* wqb = (bf16*)(ws + ((size_t)16 << 20));
  bf16* wkb = (bf16*)(ws + ((size_t)18 << 20));
  bf16* wvb = (bf16*)(ws + ((size_t)20 << 20));
  bf16* cqw = (bf16*)(ws + ((size_t)22 << 20));
  bf16* ckw = (bf16*)(ws + ((size_t)30 << 20));
  bf16* vtw = (bf16*)(ws + ((size_t)38 << 20));

  prep_x_kernel<<<dim3(2048), dim3(256), 0, stream>>>(x, tok, xb, xt);
  prep_w_kernel<<<dim3(1536), dim3(256), 0, stream>>>(Wq, Wk, Wv, wqb);
  qkv_gemm_kernel<<<dim3(32, 8, 3), dim3(256), 0, stream>>>(
      xt, xb, wqb, wkb, wvb, bq, bk, bv, cqw, ckw, vtw);
  attn_kernel<<<dim3(16, 64), dim3(256), 0, stream>>>(cqw, ckw, vtw, out);
}

// Round 4
// 95.428 us; speedup vs baseline: 1.3000x; 1.0310x over previous
//
#include <hip/hip_runtime.h>
#include <hip/hip_bf16.h>

// GuideAttentionModule: out = softmax((Q+tQ)(K+tK)^T/8) V, fused via
//   xt = x + tokens;  cQ = (xt@Wq.T + 2bq)*(0.125*log2e) ; cK = xt@Wk.T + 2bk ;
//   Vt = (x@Wv.T + bv)^T
// GEMMs: bf16 MFMA 16x16x32, fp32 acc, BK=64, 128B-row XOR-swizzled LDS,
// 2-phase double-buffered staging (T3-minimum), z-major XCD block ordering.
// Attention: flash, swapped QK^T (S^T = mfma(K,Q)), lane-local softmax,
// log2-domain, double-buffered K/V staging, O^T + LDS transpose epilogue.

typedef __bf16 bf16;
typedef __bf16 bf16x4 __attribute__((ext_vector_type(4)));
typedef __bf16 bf16x8 __attribute__((ext_vector_type(8)));
typedef float  f32x4  __attribute__((ext_vector_type(4)));

#define LOG2E 1.4426950408889634f

__device__ __forceinline__ void gll16(const void* g, void* l) {
  __builtin_amdgcn_global_load_lds(
      (const __attribute__((address_space(1))) unsigned int*)g,
      (__attribute__((address_space(3))) unsigned int*)l, 16, 0, 0);
}

// ---------- fused prep: xb/xt (blocks 0..2047), W->bf16 (blocks 2048..3583) ----------
__global__ void prep_kernel(const float* __restrict__ x, const float* __restrict__ tok,
                            const float* __restrict__ wq, const float* __restrict__ wk,
                            const float* __restrict__ wv,
                            bf16* __restrict__ xb, bf16* __restrict__ xt,
                            bf16* __restrict__ wdst) {
  const int bid = blockIdx.x;
  if (bid < 2048) {
    const size_t e = ((size_t)bid * 256 + threadIdx.x) * 8;  // 4M elems
    const int b = (int)(e >> 20);          // S*D = 1M per batch
    const int d = (int)(e & 1023);
    const float4 a0 = *(const float4*)(x + e);
    const float4 a1 = *(const float4*)(x + e + 4);
    const float4 t0 = *(const float4*)(tok + b * 1024 + d);
    const float4 t1 = *(const float4*)(tok + b * 1024 + d + 4);
    bf16x8 vb, vt;
    vb[0]=(bf16)a0.x; vb[1]=(bf16)a0.y; vb[2]=(bf16)a0.z; vb[3]=(bf16)a0.w;
    vb[4]=(bf16)a1.x; vb[5]=(bf16)a1.y; vb[6]=(bf16)a1.z; vb[7]=(bf16)a1.w;
    vt[0]=(bf16)(a0.x+t0.x); vt[1]=(bf16)(a0.y+t0.y); vt[2]=(bf16)(a0.z+t0.z); vt[3]=(bf16)(a0.w+t0.w);
    vt[4]=(bf16)(a1.x+t1.x); vt[5]=(bf16)(a1.y+t1.y); vt[6]=(bf16)(a1.z+t1.z); vt[7]=(bf16)(a1.w+t1.w);
    *(bf16x8*)(xb + e) = vb;
    *(bf16x8*)(xt + e) = vt;
  } else {
    const size_t e = ((size_t)(bid - 2048) * 256 + threadIdx.x) * 8;  // 3M elems
    const float* src; size_t off;
    if (e < (size_t)(1u<<20))      { src = wq; off = e; }
    else if (e < (size_t)(2u<<20)) { src = wk; off = e - (1u<<20); }
    else                           { src = wv; off = e - (2u<<20); }
    const float4 a0 = *(const float4*)(src + off);
    const float4 a1 = *(const float4*)(src + off + 4);
    bf16x8 v;
    v[0]=(bf16)a0.x; v[1]=(bf16)a0.y; v[2]=(bf16)a0.z; v[3]=(bf16)a0.w;
    v[4]=(bf16)a1.x; v[5]=(bf16)a1.y; v[6]=(bf16)a1.z; v[7]=(bf16)a1.w;
    *(bf16x8*)(wdst + e) = v;
  }
}

// ---------- QKV projection GEMM: C[m,n] = sum_k A[m,k]*B[n,k] ----------
// BK=64, 128B LDS rows, chunk ^ (row&7) swizzle, 2-phase dbuf staging.
// 1D grid 768: xcd = wgid&7, per-XCD z-major (z0: p 0..31, z1: 32..63, z2: 64..95)
// -> per-generation L2 footprint ~3MB < 4MB.
// z=0: A=xt[4096,1024] B=Wq -> cQ [B,H,S,hd] bf16, scaled 0.125*log2e, bias 2*bq
// z=1: A=xt            B=Wk -> cK [B,H,S,hd] bf16, bias 2*bk
// z=2: A=Wv[1024,1024] B=xb[4096,1024] -> Vt [B,H,hd,S] bf16, bias bv (along m)
__global__ __launch_bounds__(256) void qkv_gemm_kernel(
    const bf16* __restrict__ xt, const bf16* __restrict__ xb,
    const bf16* __restrict__ wq, const bf16* __restrict__ wk, const bf16* __restrict__ wv,
    const float* __restrict__ bq, const float* __restrict__ bk, const float* __restrict__ bv,
    bf16* __restrict__ cq, bf16* __restrict__ ck, bf16* __restrict__ vt)
{
  __shared__ __align__(16) char As[32768];   // 2 x (128 rows x 128B)
  __shared__ __align__(16) char Bs[32768];
  const int t = threadIdx.x, w = t >> 6, l = t & 63, g = l >> 4, c = l & 15;
  const int wgid = blockIdx.x;
  const int xcd = wgid & 7;
  const int p = wgid >> 3;        // 0..95, z-major per XCD
  const int z = p >> 5;
  const int q = p & 31;
  const int tmx = xcd * 4 + (q & 3);   // 0..31 (4 contiguous m-tiles per XCD)
  const int tny = q >> 2;              // 0..7
  const bf16 *A, *B; const float* bias; bf16* outp;
  int tm, tn;
  if (z == 0)      { A = xt; B = wq; bias = bq; outp = cq; tm = tmx; tn = tny; }
  else if (z == 1) { A = xt; B = wk; bias = bk; outp = ck; tm = tmx; tn = tny; }
  else             { A = wv; B = xb; bias = bv; outp = vt; tm = tny; tn = tmx; }
  const int m0 = tm * 128, n0 = tn * 128;
  const int wr = w >> 1, wc = w & 1;

  f32x4 acc[4][4] = {};
  // staging: thread t writes LDS linear (round*4096 + t*16); LDS(row, pchunk)
  // holds global (row, kchunk = pchunk ^ (row&7)). row = round*32 + (t>>3).
  const int lr0 = t >> 3, pc = t & 7;
  const size_t ssw = (size_t)lr0 * 2048 + (size_t)((pc ^ (lr0 & 7)) << 4);
  const char* agb = (const char*)A + (size_t)m0 * 2048 + ssw;
  const char* bgb = (const char*)B + (size_t)n0 * 2048 + ssw;

#define GSTAGE(buf, k0)                                                  \
  {                                                                      \
    const char* ag = agb + (size_t)(k0) * 2;                             \
    const char* bg = bgb + (size_t)(k0) * 2;                             \
    char* ad = As + (buf) * 16384 + w * 1024;                            \
    char* bd = Bs + (buf) * 16384 + w * 1024;                            \
    _Pragma("unroll")                                                    \
    for (int i = 0; i < 4; ++i) {                                        \
      gll16(ag + i * 65536, ad + i * 4096);   /* +32 rows * 2048B */     \
      gll16(bg + i * 65536, bd + i * 4096);                              \
    }                                                                    \
  }

  GSTAGE(0, 0);
  __syncthreads();
  int buf = 0;

  for (int k0 = 0; k0 < 1024; k0 += 64) {
    if (k0 + 64 < 1024) GSTAGE(buf ^ 1, k0 + 64);   // prefetch hides under compute
    const char* Ab = As + buf * 16384;
    const char* Bb = Bs + buf * 16384;
#pragma unroll
    for (int kf = 0; kf < 2; ++kf) {
      bf16x8 af[4], bfr[4];
#pragma unroll
      for (int mf = 0; mf < 4; ++mf) {
        const int row = wr * 64 + mf * 16 + c;
        af[mf] = *(const bf16x8*)(Ab + row * 128 + (((kf * 4 + g) ^ (row & 7)) << 4));
      }
#pragma unroll
      for (int nf = 0; nf < 4; ++nf) {
        const int row = wc * 64 + nf * 16 + c;
        bfr[nf] = *(const bf16x8*)(Bb + row * 128 + (((kf * 4 + g) ^ (row & 7)) << 4));
      }
#pragma unroll
      for (int mf = 0; mf < 4; ++mf)
#pragma unroll
        for (int nf = 0; nf < 4; ++nf)
          acc[mf][nf] = __builtin_amdgcn_mfma_f32_16x16x32_bf16(af[mf], bfr[nf], acc[mf][nf], 0, 0, 0);
    }
    __syncthreads();   // prefetch landed (vmcnt drain) + all waves done with buf
    buf ^= 1;
  }
#undef GSTAGE

  // epilogue: D layout col=lane&15, row=(lane>>4)*4+r   [m89]
  if (z < 2) {
    const float sc = (z == 0) ? 0.125f * LOG2E : 1.0f;  // fold 1/sqrt(hd), log2e into cQ
#pragma unroll
    for (int mf = 0; mf < 4; ++mf)
#pragma unroll
      for (int nf = 0; nf < 4; ++nf) {
        const int n = n0 + wc * 64 + nf * 16 + c;
        const int h = n >> 6, d = n & 63;
        const float bsum = 2.0f * bias[n];
#pragma unroll
        for (int r = 0; r < 4; ++r) {
          const int m = m0 + wr * 64 + mf * 16 + g * 4 + r;
          const int b = m >> 10, s = m & 1023;
          outp[(((size_t)(b * 16 + h)) * 1024 + s) * 64 + d] = (bf16)((acc[mf][nf][r] + bsum) * sc);
        }
      }
  } else {
#pragma unroll
    for (int mf = 0; mf < 4; ++mf)
#pragma unroll
      for (int nf = 0; nf < 4; ++nf) {
        const int n = n0 + wc * 64 + nf * 16 + c;   // x-row
        const int b = n >> 10, s = n & 1023;
#pragma unroll
        for (int r = 0; r < 4; ++r) {
          const int m = m0 + wr * 64 + mf * 16 + g * 4 + r;  // v-dim
          const int h = m >> 6, d = m & 63;
          outp[(((size_t)(b * 16 + h)) * 64 + d) * 1024 + s] = (bf16)(acc[mf][nf][r] + bias[m]);
        }
      }
  }
}

// ---------- flash attention (swapped QK^T, 2-phase dbuf) ----------
__global__ __launch_bounds__(256) void attn_kernel(
    const bf16* __restrict__ cq, const bf16* __restrict__ ck, const bf16* __restrict__ vt,
    float* __restrict__ out)
{
  __shared__ __align__(16) char LDS[40960];
  const int t = threadIdx.x, w = t >> 6, l = t & 63, g = l >> 4, c = l & 15;
  const int bh = blockIdx.y, qt = blockIdx.x;
  const int b = bh >> 4, h = bh & 15;
  const bf16* cqb = cq + (size_t)bh * 65536;
  const bf16* ckb = ck + (size_t)bh * 65536;
  const bf16* vtb = vt + (size_t)bh * 65536;
  const int q0 = qt * 64 + w * 16;
  char* Ps = LDS + 32768 + w * 2048;

  // Q as B-fragment: lane (g,c) holds cQ[q0+c][kf*32 + g*8 + j]
  bf16x8 qf[2];
#pragma unroll
  for (int kf = 0; kf < 2; ++kf)
    qf[kf] = *(const bf16x8*)(cqb + (size_t)(q0 + c) * 64 + kf * 32 + g * 8);

  f32x4 o[4] = {};                       // O^T: o[nd][r] = O[q=c][d=nd*16+g*4+r]
  float m = -INFINITY, lsum = 0.f;       // per q=c (replicated across g)

  const int srow = t >> 3;               // staging row 0..31
  const int sch  = (t & 7) ^ (srow & 7); // pre-swizzled 16B chunk
  const size_t ksrc = (size_t)srow * 128  + (size_t)sch * 16;
  const size_t vsrc = (size_t)srow * 2048 + (size_t)sch * 16;

#define STAGE(buf, t0)                                                   \
  {                                                                      \
    const char* kgb = (const char*)ckb + (size_t)(t0) * 128;             \
    const char* vgb = (const char*)vtb + (size_t)(t0) * 2;               \
    char* kd = LDS + (buf) * 8192 + w * 1024;                            \
    char* vd = LDS + 16384 + (buf) * 8192 + w * 1024;                    \
    gll16(kgb + ksrc,         kd);                                       \
    gll16(kgb + 4096 + ksrc,  kd + 4096);  /* rows 32..63 */             \
    gll16(vgb + vsrc,         vd);                                       \
    gll16(vgb + 65536 + vsrc, vd + 4096);  /* d-rows 32..63 */           \
  }

  STAGE(0, 0);
  __syncthreads();
  int buf = 0;

  for (int t0 = 0; t0 < 1024; t0 += 64) {
    if (t0 + 64 < 1024) STAGE(buf ^ 1, t0 + 64);
    const char* Kb = LDS + buf * 8192;
    const char* Vb = LDS + 16384 + buf * 8192;

    // S^T = K·Q^T : s[nf][r] = S[key=nf*16+g*4+r][q=c]  (log2 units)
    f32x4 s[4] = {};
#pragma unroll
    for (int kf = 0; kf < 2; ++kf)
#pragma unroll
      for (int nf = 0; nf < 4; ++nf) {
        const int kr = nf * 16 + c;
        bf16x8 kb = *(const bf16x8*)(Kb + kr * 128 + (((kf * 4 + g) ^ (kr & 7)) << 4));
        s[nf] = __builtin_amdgcn_mfma_f32_16x16x32_bf16(kb, qf[kf], s[nf], 0, 0, 0);
      }

    // lane-local softmax for q=c: 16 own scores + 2 shuffles per reduce
    float vmax = s[0][0];
#pragma unroll
    for (int nf = 0; nf < 4; ++nf)
#pragma unroll
      for (int r = 0; r < 4; ++r) vmax = fmaxf(vmax, s[nf][r]);
    vmax = fmaxf(vmax, __shfl_xor(vmax, 16, 64));
    vmax = fmaxf(vmax, __shfl_xor(vmax, 32, 64));
    const float mnew = fmaxf(m, vmax);
    const float alpha = exp2f(m - mnew);
    m = mnew;

    float p[4][4];
    float ps = 0.f;
#pragma unroll
    for (int nf = 0; nf < 4; ++nf)
#pragma unroll
      for (int r = 0; r < 4; ++r) {
        p[nf][r] = exp2f(s[nf][r] - mnew);
        ps += p[nf][r];
      }
    // pack P -> LDS (wave-private, swizzled): row q=c, keys nf*16+g*4..+3
#pragma unroll
    for (int nf = 0; nf < 4; ++nf) {
      bf16x4 pw;
      pw[0] = (bf16)p[nf][0]; pw[1] = (bf16)p[nf][1];
      pw[2] = (bf16)p[nf][2]; pw[3] = (bf16)p[nf][3];
      const int byteoff = (nf * 32 + g * 8) ^ ((c & 7) << 4);
      *(bf16x4*)(Ps + c * 128 + byteoff) = pw;
    }
    ps += __shfl_xor(ps, 16, 64);
    ps += __shfl_xor(ps, 32, 64);
    lsum = lsum * alpha + ps;
#pragma unroll
    for (int nd = 0; nd < 4; ++nd) o[nd] *= alpha;

    // O^T += Vt·P^T : A = Vt rows d, B = P^T (lane (g,c): P[q=c][kf*32+g*8+j])
    bf16x8 pa[2];
#pragma unroll
    for (int kf = 0; kf < 2; ++kf)
      pa[kf] = *(const bf16x8*)(Ps + c * 128 + (((kf * 4 + g) ^ (c & 7)) << 4));
#pragma unroll
    for (int kf = 0; kf < 2; ++kf)
#pragma unroll
      for (int nd = 0; nd < 4; ++nd) {
        const int vr = nd * 16 + c;
        bf16x8 vb = *(const bf16x8*)(Vb + vr * 128 + (((kf * 4 + g) ^ (vr & 7)) << 4));
        o[nd] = __builtin_amdgcn_mfma_f32_16x16x32_bf16(vb, pa[kf], o[nd], 0, 0, 0);
      }

    __syncthreads();   // staged buf^1 landed (vmcnt drain) + all waves done with buf
    buf ^= 1;
  }

#undef STAGE

  // epilogue: transpose O^T through LDS (reuse K region, 64x64 fp32, swizzled)
  const float inv = 1.0f / lsum;
  {
    char* Ob = LDS;  // [64 rows q][16 chunks of 16B]
    const int row = w * 16 + c;
#pragma unroll
    for (int nd = 0; nd < 4; ++nd) {
      f32x4 vo = o[nd] * inv;
      const int pch = (nd * 4 + g) ^ (row & 7);   // physical chunk
      *(f32x4*)(Ob + row * 256 + (pch << 4)) = vo;
    }
  }
  __syncthreads();
  {
    const int rr = t >> 2;                 // output row 0..63
    float* orow = out + ((size_t)(b * 1024 + qt * 64 + rr)) * 1024 + h * 64;
#pragma unroll
    for (int i = 0; i < 4; ++i) {
      const int ch = (t & 3) + i * 4;      // data chunk = d/4
      f32x4 v = *(const f32x4*)(LDS + rr * 256 + ((ch ^ (rr & 7)) << 4));
      *(f32x4*)(orow + ch * 4) = v;
    }
  }
}

extern "C" void kernel_launch(void* const* d_in, const int* in_sizes, int n_in,
                              void* d_out, int out_size, void* d_ws, size_t ws_size,
                              hipStream_t stream) {
  const float* x   = (const float*)d_in[0];
  const float* tok = (const float*)d_in[1];
  const float* Wq  = (const float*)d_in[2];
  const float* bq  = (const float*)d_in[3];
  const float* Wk  = (const float*)d_in[4];
  const float* bk  = (const float*)d_in[5];
  const float* Wv  = (const float*)d_in[6];
  const float* bv  = (const float*)d_in[7];
  float* out = (float*)d_out;
  char* ws = (char*)d_ws;
  // workspace layout (46 MB total)
  bf16* xt  = (bf16*)(ws + (size_t)0);
  bf16* xb  = (bf16*)(ws + ((size_t)8  << 20));
  bf16* wqb = (bf16*)(ws + ((size_t)16 << 20));
  bf16* wkb = (bf16*)(ws + ((size_t)18 << 20));
  bf16* wvb = (bf16*)(ws + ((size_t)20 << 20));
  bf16* cqw = (bf16*)(ws + ((size_t)22 << 20));
  bf16* ckw = (bf16*)(ws + ((size_t)30 << 20));
  bf16* vtw = (bf16*)(ws + ((size_t)38 << 20));

  prep_kernel<<<dim3(3584), dim3(256), 0, stream>>>(x, tok, Wq, Wk, Wv, xb, xt, wqb);
  qkv_gemm_kernel<<<dim3(768), dim3(256), 0, stream>>>(
      xt, xb, wqb, wkb, wvb, bq, bk, bv, cqw, ckw, vtw);
  attn_kernel<<<dim3(16, 64), dim3(256), 0, stream>>>(cqw, ckw, vtw, out);
}

// Round 6
// 90.635 us; speedup vs baseline: 1.3688x; 1.0529x over previous
//
#include <hip/hip_runtime.h>
#include <hip/hip_bf16.h>

// GuideAttentionModule: out = softmax((Q+tQ)(K+tK)^T/8) V, fused via
//   xt = x + tokens;  cQ = (xt@Wq.T + 2bq)*(0.125*log2e) ; cK = xt@Wk.T + 2bk ;
//   Vt = (x@Wv.T + bv)^T
// GEMM: 256x256 tile, BK=64, 8 waves (2Mx4N), phase-interleaved schedule with
// counted vmcnt (never drained mid-loop), raw s_barrier, setprio around MFMA
// (T3+T4+T5), XOR-swizzled LDS, XCD-bijective z-major grid.
// vmcnt derivation (T4): GSTAGE issues 8 global_load_lds per thread; at the
// wait point outstanding = 8 (tile kt) + 8 (tile kt+1 just issued) -> wait
// vmcnt(8) so tile kt's 8 have landed, tile kt+1's stay in flight.
// Attention: flash, swapped QK^T (S^T = mfma(K,Q)), lane-local softmax,
// log2-domain, double-buffered K/V staging, O^T + LDS transpose epilogue.

typedef __bf16 bf16;
typedef __bf16 bf16x4 __attribute__((ext_vector_type(4)));
typedef __bf16 bf16x8 __attribute__((ext_vector_type(8)));
typedef float  f32x4  __attribute__((ext_vector_type(4)));

#define LOG2E 1.4426950408889634f

__device__ __forceinline__ void gll16(const void* g, void* l) {
  __builtin_amdgcn_global_load_lds(
      (const __attribute__((address_space(1))) unsigned int*)g,
      (__attribute__((address_space(3))) unsigned int*)l, 16, 0, 0);
}

// ---------- fused prep: xb/xt (blocks 0..2047), W->bf16 (blocks 2048..3583) ----------
__global__ void prep_kernel(const float* __restrict__ x, const float* __restrict__ tok,
                            const float* __restrict__ wq, const float* __restrict__ wk,
                            const float* __restrict__ wv,
                            bf16* __restrict__ xb, bf16* __restrict__ xt,
                            bf16* __restrict__ wdst) {
  const int bid = blockIdx.x;
  if (bid < 2048) {
    const size_t e = ((size_t)bid * 256 + threadIdx.x) * 8;  // 4M elems
    const int b = (int)(e >> 20);          // S*D = 1M per batch
    const int d = (int)(e & 1023);
    const float4 a0 = *(const float4*)(x + e);
    const float4 a1 = *(const float4*)(x + e + 4);
    const float4 t0 = *(const float4*)(tok + b * 1024 + d);
    const float4 t1 = *(const float4*)(tok + b * 1024 + d + 4);
    bf16x8 vb, vt;
    vb[0]=(bf16)a0.x; vb[1]=(bf16)a0.y; vb[2]=(bf16)a0.z; vb[3]=(bf16)a0.w;
    vb[4]=(bf16)a1.x; vb[5]=(bf16)a1.y; vb[6]=(bf16)a1.z; vb[7]=(bf16)a1.w;
    vt[0]=(bf16)(a0.x+t0.x); vt[1]=(bf16)(a0.y+t0.y); vt[2]=(bf16)(a0.z+t0.z); vt[3]=(bf16)(a0.w+t0.w);
    vt[4]=(bf16)(a1.x+t1.x); vt[5]=(bf16)(a1.y+t1.y); vt[6]=(bf16)(a1.z+t1.z); vt[7]=(bf16)(a1.w+t1.w);
    *(bf16x8*)(xb + e) = vb;
    *(bf16x8*)(xt + e) = vt;
  } else {
    const size_t e = ((size_t)(bid - 2048) * 256 + threadIdx.x) * 8;  // 3M elems
    const float* src; size_t off;
    if (e < (size_t)(1u<<20))      { src = wq; off = e; }
    else if (e < (size_t)(2u<<20)) { src = wk; off = e - (1u<<20); }
    else                           { src = wv; off = e - (2u<<20); }
    const float4 a0 = *(const float4*)(src + off);
    const float4 a1 = *(const float4*)(src + off + 4);
    bf16x8 v;
    v[0]=(bf16)a0.x; v[1]=(bf16)a0.y; v[2]=(bf16)a0.z; v[3]=(bf16)a0.w;
    v[4]=(bf16)a1.x; v[5]=(bf16)a1.y; v[6]=(bf16)a1.z; v[7]=(bf16)a1.w;
    *(bf16x8*)(wdst + e) = v;
  }
}

// ---------- QKV projection GEMM: C[m,n] = sum_k A[m,k]*B[n,k] ----------
// 256x256 tile, BK=64 (16 K-tiles), 512 thr / 8 waves: wm=w>>2, wn=w&3,
// per-wave output 128x64. 2 LDS slots; stage tile kt+1 at top of body kt,
// s_waitcnt vmcnt(8) (tile kt landed, kt+1's 8 loads in flight), raw s_barrier.
// 4 phases/K-tile: quadrant (pm,pn), 16 MFMA each, setprio(1) around cluster.
// grid 192 = 3z x 64 tiles; xcd = wgid&7, z-major per XCD.
__global__ __launch_bounds__(512, 2) void qkv_gemm_kernel(
    const bf16* __restrict__ xt, const bf16* __restrict__ xb,
    const bf16* __restrict__ wq, const bf16* __restrict__ wk, const bf16* __restrict__ wv,
    const float* __restrict__ bq, const float* __restrict__ bk, const float* __restrict__ bv,
    bf16* __restrict__ cq, bf16* __restrict__ ck, bf16* __restrict__ vt)
{
  __shared__ __align__(16) char LDSG[131072];   // A: 2x32KB | B: 2x32KB
  char* As = LDSG;
  char* Bs = LDSG + 65536;
  const int t = threadIdx.x, w = t >> 6, l = t & 63, g = l >> 4, c = l & 15;
  const int wm = w >> 2, wn = w & 3;
  const int wgid = blockIdx.x;
  const int xcd = wgid & 7;        // HW round-robins consecutive wgids over XCDs
  const int p = wgid >> 3;         // 0..23 per XCD, z-major
  const int z = p >> 3;            // 0..2
  const int q = p & 7;             // 0..7
  const bf16 *A, *B; const float* bias; bf16* outp;
  int tm, tn;
  if (z < 2) { tm = xcd * 2 + (q & 1); tn = q >> 1; }       // 16 x 4 tiles
  else       { tm = q >> 1; tn = xcd * 2 + (q & 1); }       // 4 x 16 tiles
  if (z == 0)      { A = xt; B = wq; bias = bq; outp = cq; }
  else if (z == 1) { A = xt; B = wk; bias = bk; outp = ck; }
  else             { A = wv; B = xb; bias = bv; outp = vt; }
  const int m0 = tm * 256, n0 = tn * 256;

  f32x4 acc[8][4] = {};   // [mf: wm*128 + mf*16][nf: wn*64 + nf*16]

  // staging: 512 threads, round i covers rows i*64 + (t>>3), 16B chunk t&7.
  // LDS linear dest; global source pre-swizzled so LDS(row,pc) holds global
  // chunk pc ^ (row&7)  (rule #21; read side applies the same XOR).
  const int lr = t >> 3, pc = t & 7;
  const size_t ssw = (size_t)lr * 2048 + (size_t)((pc ^ (lr & 7)) << 4);
  const char* agb = (const char*)A + (size_t)m0 * 2048 + ssw;
  const char* bgb = (const char*)B + (size_t)n0 * 2048 + ssw;

#define GSTAGE(slot, kt)                                                 \
  {                                                                      \
    const size_t ko = (size_t)(kt) * 128;   /* 64 k-elems * 2B */        \
    char* ad = As + (slot) * 32768 + t * 16;                             \
    char* bd = Bs + (slot) * 32768 + t * 16;                             \
    _Pragma("unroll")                                                    \
    for (int i = 0; i < 4; ++i) {          /* 4 rounds x 64 rows */      \
      gll16(agb + ko + (size_t)i * 131072, ad + i * 8192);               \
      gll16(bgb + ko + (size_t)i * 131072, bd + i * 8192);               \
    }                                                                    \
  }

  GSTAGE(0, 0);
  for (int kt = 0; kt < 16; ++kt) {
    const int s = kt & 1;
    if (kt < 15) {
      GSTAGE(s ^ 1, kt + 1);   // slot s^1 last read in kt-1; end barrier passed
      // 8 loads of tile kt (maybe unlanded) + 8 just issued = 16 outstanding;
      // wait to 8 -> tile kt landed, tile kt+1 stays in flight.
      asm volatile("s_waitcnt vmcnt(8)" ::: "memory");
    } else {
      asm volatile("s_waitcnt vmcnt(0)" ::: "memory");
    }
    __builtin_amdgcn_sched_barrier(0);
    __builtin_amdgcn_s_barrier();          // everyone's tile-kt portion landed

    const char* Ab = As + s * 32768;
    const char* Bb = Bs + s * 32768;
    // ---- phase 0: read B(all)+A(lo); MFMA quadrant (pm0,pn0) ----
    bf16x8 bfr[4][2], af[4][2];
#pragma unroll
    for (int nf = 0; nf < 4; ++nf)
#pragma unroll
      for (int kf = 0; kf < 2; ++kf) {
        const int row = wn * 64 + nf * 16 + c;
        bfr[nf][kf] = *(const bf16x8*)(Bb + row * 128 + (((kf * 4 + g) ^ (row & 7)) << 4));
      }
#pragma unroll
    for (int mf = 0; mf < 4; ++mf)
#pragma unroll
      for (int kf = 0; kf < 2; ++kf) {
        const int row = wm * 128 + mf * 16 + c;
        af[mf][kf] = *(const bf16x8*)(Ab + row * 128 + (((kf * 4 + g) ^ (row & 7)) << 4));
      }
    __builtin_amdgcn_s_setprio(1);
#pragma unroll
    for (int mf = 0; mf < 4; ++mf)
#pragma unroll
      for (int nf = 0; nf < 2; ++nf)
#pragma unroll
        for (int kf = 0; kf < 2; ++kf)
          acc[mf][nf] = __builtin_amdgcn_mfma_f32_16x16x32_bf16(af[mf][kf], bfr[nf][kf], acc[mf][nf], 0, 0, 0);
    __builtin_amdgcn_s_setprio(0);
    __builtin_amdgcn_s_barrier();
    // ---- phase 1: MFMA quadrant (pm0,pn1) ----
    __builtin_amdgcn_s_setprio(1);
#pragma unroll
    for (int mf = 0; mf < 4; ++mf)
#pragma unroll
      for (int nf = 0; nf < 2; ++nf)
#pragma unroll
        for (int kf = 0; kf < 2; ++kf)
          acc[mf][2 + nf] = __builtin_amdgcn_mfma_f32_16x16x32_bf16(af[mf][kf], bfr[2 + nf][kf], acc[mf][2 + nf], 0, 0, 0);
    __builtin_amdgcn_s_setprio(0);
    __builtin_amdgcn_s_barrier();
    // ---- phase 2: read A(hi); MFMA quadrant (pm1,pn0) ----
#pragma unroll
    for (int mf = 0; mf < 4; ++mf)
#pragma unroll
      for (int kf = 0; kf < 2; ++kf) {
        const int row = wm * 128 + 64 + mf * 16 + c;
        af[mf][kf] = *(const bf16x8*)(Ab + row * 128 + (((kf * 4 + g) ^ (row & 7)) << 4));
      }
    __builtin_amdgcn_s_setprio(1);
#pragma unroll
    for (int mf = 0; mf < 4; ++mf)
#pragma unroll
      for (int nf = 0; nf < 2; ++nf)
#pragma unroll
        for (int kf = 0; kf < 2; ++kf)
          acc[4 + mf][nf] = __builtin_amdgcn_mfma_f32_16x16x32_bf16(af[mf][kf], bfr[nf][kf], acc[4 + mf][nf], 0, 0, 0);
    __builtin_amdgcn_s_setprio(0);
    __builtin_amdgcn_s_barrier();
    // ---- phase 3: MFMA quadrant (pm1,pn1) ----
    __builtin_amdgcn_s_setprio(1);
#pragma unroll
    for (int mf = 0; mf < 4; ++mf)
#pragma unroll
      for (int nf = 0; nf < 2; ++nf)
#pragma unroll
        for (int kf = 0; kf < 2; ++kf)
          acc[4 + mf][2 + nf] = __builtin_amdgcn_mfma_f32_16x16x32_bf16(af[mf][kf], bfr[2 + nf][kf], acc[4 + mf][2 + nf], 0, 0, 0);
    __builtin_amdgcn_s_setprio(0);
    asm volatile("s_waitcnt lgkmcnt(0)" ::: "memory");
    __builtin_amdgcn_s_barrier();          // end-of-tile: slot s free for kt+2
  }
#undef GSTAGE

  // epilogue: D layout col=lane&15, row=(lane>>4)*4+r   [m89]
  if (z < 2) {
    const float sc = (z == 0) ? 0.125f * LOG2E : 1.0f;  // fold 1/sqrt(hd), log2e into cQ
#pragma unroll
    for (int mf = 0; mf < 8; ++mf)
#pragma unroll
      for (int nf = 0; nf < 4; ++nf) {
        const int n = n0 + wn * 64 + nf * 16 + c;
        const int h = n >> 6, d = n & 63;
        const float bsum = 2.0f * bias[n];
#pragma unroll
        for (int r = 0; r < 4; ++r) {
          const int m = m0 + wm * 128 + mf * 16 + g * 4 + r;
          const int b = m >> 10, s = m & 1023;
          outp[(((size_t)(b * 16 + h)) * 1024 + s) * 64 + d] = (bf16)((acc[mf][nf][r] + bsum) * sc);
        }
      }
  } else {
#pragma unroll
    for (int mf = 0; mf < 8; ++mf)
#pragma unroll
      for (int nf = 0; nf < 4; ++nf) {
        const int n = n0 + wn * 64 + nf * 16 + c;   // x-row
        const int b = n >> 10, s = n & 1023;
#pragma unroll
        for (int r = 0; r < 4; ++r) {
          const int m = m0 + wm * 128 + mf * 16 + g * 4 + r;  // v-dim
          const int h = m >> 6, d = m & 63;
          outp[(((size_t)(b * 16 + h)) * 64 + d) * 1024 + s] = (bf16)(acc[mf][nf][r] + bias[m]);
        }
      }
  }
}

// ---------- flash attention (swapped QK^T, 2-phase dbuf) ----------
__global__ __launch_bounds__(256) void attn_kernel(
    const bf16* __restrict__ cq, const bf16* __restrict__ ck, const bf16* __restrict__ vt,
    float* __restrict__ out)
{
  __shared__ __align__(16) char LDS[40960];
  const int t = threadIdx.x, w = t >> 6, l = t & 63, g = l >> 4, c = l & 15;
  const int bh = blockIdx.y, qt = blockIdx.x;
  const int b = bh >> 4, h = bh & 15;
  const bf16* cqb = cq + (size_t)bh * 65536;
  const bf16* ckb = ck + (size_t)bh * 65536;
  const bf16* vtb = vt + (size_t)bh * 65536;
  const int q0 = qt * 64 + w * 16;
  char* Ps = LDS + 32768 + w * 2048;

  // Q as B-fragment: lane (g,c) holds cQ[q0+c][kf*32 + g*8 + j]
  bf16x8 qf[2];
#pragma unroll
  for (int kf = 0; kf < 2; ++kf)
    qf[kf] = *(const bf16x8*)(cqb + (size_t)(q0 + c) * 64 + kf * 32 + g * 8);

  f32x4 o[4] = {};                       // O^T: o[nd][r] = O[q=c][d=nd*16+g*4+r]
  float m = -INFINITY, lsum = 0.f;       // per q=c (replicated across g)

  const int srow = t >> 3;               // staging row 0..31
  const int sch  = (t & 7) ^ (srow & 7); // pre-swizzled 16B chunk
  const size_t ksrc = (size_t)srow * 128  + (size_t)sch * 16;
  const size_t vsrc = (size_t)srow * 2048 + (size_t)sch * 16;

#define STAGE(buf, t0)                                                   \
  {                                                                      \
    const char* kgb = (const char*)ckb + (size_t)(t0) * 128;             \
    const char* vgb = (const char*)vtb + (size_t)(t0) * 2;               \
    char* kd = LDS + (buf) * 8192 + w * 1024;                            \
    char* vd = LDS + 16384 + (buf) * 8192 + w * 1024;                    \
    gll16(kgb + ksrc,         kd);                                       \
    gll16(kgb + 4096 + ksrc,  kd + 4096);  /* rows 32..63 */             \
    gll16(vgb + vsrc,         vd);                                       \
    gll16(vgb + 65536 + vsrc, vd + 4096);  /* d-rows 32..63 */           \
  }

  STAGE(0, 0);
  __syncthreads();
  int buf = 0;

  for (int t0 = 0; t0 < 1024; t0 += 64) {
    if (t0 + 64 < 1024) STAGE(buf ^ 1, t0 + 64);
    const char* Kb = LDS + buf * 8192;
    const char* Vb = LDS + 16384 + buf * 8192;

    // S^T = K·Q^T : s[nf][r] = S[key=nf*16+g*4+r][q=c]  (log2 units)
    f32x4 s[4] = {};
#pragma unroll
    for (int kf = 0; kf < 2; ++kf)
#pragma unroll
      for (int nf = 0; nf < 4; ++nf) {
        const int kr = nf * 16 + c;
        bf16x8 kb = *(const bf16x8*)(Kb + kr * 128 + (((kf * 4 + g) ^ (kr & 7)) << 4));
        s[nf] = __builtin_amdgcn_mfma_f32_16x16x32_bf16(kb, qf[kf], s[nf], 0, 0, 0);
      }

    // lane-local softmax for q=c: 16 own scores + 2 shuffles per reduce
    float vmax = s[0][0];
#pragma unroll
    for (int nf = 0; nf < 4; ++nf)
#pragma unroll
      for (int r = 0; r < 4; ++r) vmax = fmaxf(vmax, s[nf][r]);
    vmax = fmaxf(vmax, __shfl_xor(vmax, 16, 64));
    vmax = fmaxf(vmax, __shfl_xor(vmax, 32, 64));
    const float mnew = fmaxf(m, vmax);
    const float alpha = exp2f(m - mnew);
    m = mnew;

    float p[4][4];
    float ps = 0.f;
#pragma unroll
    for (int nf = 0; nf < 4; ++nf)
#pragma unroll
      for (int r = 0; r < 4; ++r) {
        p[nf][r] = exp2f(s[nf][r] - mnew);
        ps += p[nf][r];
      }
    // pack P -> LDS (wave-private, swizzled): row q=c, keys nf*16+g*4..+3
#pragma unroll
    for (int nf = 0; nf < 4; ++nf) {
      bf16x4 pw;
      pw[0] = (bf16)p[nf][0]; pw[1] = (bf16)p[nf][1];
      pw[2] = (bf16)p[nf][2]; pw[3] = (bf16)p[nf][3];
      const int byteoff = (nf * 32 + g * 8) ^ ((c & 7) << 4);
      *(bf16x4*)(Ps + c * 128 + byteoff) = pw;
    }
    ps += __shfl_xor(ps, 16, 64);
    ps += __shfl_xor(ps, 32, 64);
    lsum = lsum * alpha + ps;
#pragma unroll
    for (int nd = 0; nd < 4; ++nd) o[nd] *= alpha;

    // O^T += Vt·P^T : A = Vt rows d, B = P^T (lane (g,c): P[q=c][kf*32+g*8+j])
    bf16x8 pa[2];
#pragma unroll
    for (int kf = 0; kf < 2; ++kf)
      pa[kf] = *(const bf16x8*)(Ps + c * 128 + (((kf * 4 + g) ^ (c & 7)) << 4));
#pragma unroll
    for (int kf = 0; kf < 2; ++kf)
#pragma unroll
      for (int nd = 0; nd < 4; ++nd) {
        const int vr = nd * 16 + c;
        bf16x8 vb = *(const bf16x8*)(Vb + vr * 128 + (((kf * 4 + g) ^ (vr & 7)) << 4));
        o[nd] = __builtin_amdgcn_mfma_f32_16x16x32_bf16(vb, pa[kf], o[nd], 0, 0, 0);
      }

    __syncthreads();   // staged buf^1 landed (vmcnt drain) + all waves done with buf
    buf ^= 1;
  }

#undef STAGE

  // epilogue: transpose O^T through LDS (reuse K region, 64x64 fp32, swizzled)
  const float inv = 1.0f / lsum;
  {
    char* Ob = LDS;  // [64 rows q][16 chunks of 16B]
    const int row = w * 16 + c;
#pragma unroll
    for (int nd = 0; nd < 4; ++nd) {
      f32x4 vo = o[nd] * inv;
      const int pch = (nd * 4 + g) ^ (row & 7);   // physical chunk
      *(f32x4*)(Ob + row * 256 + (pch << 4)) = vo;
    }
  }
  __syncthreads();
  {
    const int rr = t >> 2;                 // output row 0..63
    float* orow = out + ((size_t)(b * 1024 + qt * 64 + rr)) * 1024 + h * 64;
#pragma unroll
    for (int i = 0; i < 4; ++i) {
      const int ch = (t & 3) + i * 4;      // data chunk = d/4
      f32x4 v = *(const f32x4*)(LDS + rr * 256 + ((ch ^ (rr & 7)) << 4));
      *(f32x4*)(orow + ch * 4) = v;
    }
  }
}

extern "C" void kernel_launch(void* const* d_in, const int* in_sizes, int n_in,
                              void* d_out, int out_size, void* d_ws, size_t ws_size,
                              hipStream_t stream) {
  const float* x   = (const float*)d_in[0];
  const float* tok = (const float*)d_in[1];
  const float* Wq  = (const float*)d_in[2];
  const float* bq  = (const float*)d_in[3];
  const float* Wk  = (const float*)d_in[4];
  const float* bk  = (const float*)d_in[5];
  const float* Wv  = (const float*)d_in[6];
  const float* bv  = (const float*)d_in[7];
  float* out = (float*)d_out;
  char* ws = (char*)d_ws;
  // workspace layout (46 MB total)
  bf16* xt  = (bf16*)(ws + (size_t)0);
  bf16* xb  = (bf16*)(ws + ((size_t)8  << 20));
  bf16* wqb = (bf16*)(ws + ((size_t)16 << 20));
  bf16* wkb = (bf16*)(ws + ((size_t)18 << 20));
  bf16* wvb = (bf16*)(ws + ((size_t)20 << 20));
  bf16* cqw = (bf16*)(ws + ((size_t)22 << 20));
  bf16* ckw = (bf16*)(ws + ((size_t)30 << 20));
  bf16* vtw = (bf16*)(ws + ((size_t)38 << 20));

  prep_kernel<<<dim3(3584), dim3(256), 0, stream>>>(x, tok, Wq, Wk, Wv, xb, xt, wqb);
  qkv_gemm_kernel<<<dim3(192), dim3(512), 0, stream>>>(
      xt, xb, wqb, wkb, wvb, bq, bk, bv, cqw, ckw, vtw);
  attn_kernel<<<dim3(16, 64), dim3(256), 0, stream>>>(cqw, ckw, vtw, out);
}

// Round 7
// 89.891 us; speedup vs baseline: 1.3801x; 1.0083x over previous
//
#include <hip/hip_runtime.h>
#include <hip/hip_bf16.h>

// GuideAttentionModule: out = softmax((Q+tQ)(K+tK)^T/8) V, fused via
//   xt = x + tokens;  cQ = (xt@Wq.T + 2bq)*(0.125*log2e) ; cK = xt@Wk.T + 2bk ;
//   Vt = (x@Wv.T + bv)^T
// GEMM: 256x256 tile, BK=32, 3-slot LDS rotation with prefetch depth 2,
// counted vmcnt(8) (4 loads/GSTAGE, 2 tiles in flight), raw s_barrier,
// XOR-swizzled LDS, XCD z-major grid.
// Attention: flash, swapped QK^T with PERMUTED K staging: LDS K row kr holds
// global key kap(kr) = (b4<<5)|(b3b2<<3)|(b5<<2)|(b1b0), chosen so the S^T
// output rows land in PV B-fragment slot order -> P fragment is built fully
// lane-locally with 8 v_cvt_pk_bf16_f32 (no P LDS, no conflicts). Defer-max
// rescale (T13, THR=8 in log2 domain). O^T + LDS transpose epilogue.

typedef __bf16 bf16;
typedef __bf16 bf16x8 __attribute__((ext_vector_type(8)));
typedef float  f32x4  __attribute__((ext_vector_type(4)));

#define LOG2E 1.4426950408889634f

__device__ __forceinline__ void gll16(const void* g, void* l) {
  __builtin_amdgcn_global_load_lds(
      (const __attribute__((address_space(1))) unsigned int*)g,
      (__attribute__((address_space(3))) unsigned int*)l, 16, 0, 0);
}

__device__ __forceinline__ unsigned cvtpk(float a, float b) {
  unsigned r;
  asm("v_cvt_pk_bf16_f32 %0, %1, %2" : "=v"(r) : "v"(a), "v"(b));
  return r;
}

// ---------- fused prep: xb/xt (blocks 0..2047), W->bf16 (blocks 2048..3583) ----------
__global__ void prep_kernel(const float* __restrict__ x, const float* __restrict__ tok,
                            const float* __restrict__ wq, const float* __restrict__ wk,
                            const float* __restrict__ wv,
                            bf16* __restrict__ xb, bf16* __restrict__ xt,
                            bf16* __restrict__ wdst) {
  const int bid = blockIdx.x;
  if (bid < 2048) {
    const size_t e = ((size_t)bid * 256 + threadIdx.x) * 8;  // 4M elems
    const int b = (int)(e >> 20);          // S*D = 1M per batch
    const int d = (int)(e & 1023);
    const float4 a0 = *(const float4*)(x + e);
    const float4 a1 = *(const float4*)(x + e + 4);
    const float4 t0 = *(const float4*)(tok + b * 1024 + d);
    const float4 t1 = *(const float4*)(tok + b * 1024 + d + 4);
    bf16x8 vb, vt;
    vb[0]=(bf16)a0.x; vb[1]=(bf16)a0.y; vb[2]=(bf16)a0.z; vb[3]=(bf16)a0.w;
    vb[4]=(bf16)a1.x; vb[5]=(bf16)a1.y; vb[6]=(bf16)a1.z; vb[7]=(bf16)a1.w;
    vt[0]=(bf16)(a0.x+t0.x); vt[1]=(bf16)(a0.y+t0.y); vt[2]=(bf16)(a0.z+t0.z); vt[3]=(bf16)(a0.w+t0.w);
    vt[4]=(bf16)(a1.x+t1.x); vt[5]=(bf16)(a1.y+t1.y); vt[6]=(bf16)(a1.z+t1.z); vt[7]=(bf16)(a1.w+t1.w);
    *(bf16x8*)(xb + e) = vb;
    *(bf16x8*)(xt + e) = vt;
  } else {
    const size_t e = ((size_t)(bid - 2048) * 256 + threadIdx.x) * 8;  // 3M elems
    const float* src; size_t off;
    if (e < (size_t)(1u<<20))      { src = wq; off = e; }
    else if (e < (size_t)(2u<<20)) { src = wk; off = e - (1u<<20); }
    else                           { src = wv; off = e - (2u<<20); }
    const float4 a0 = *(const float4*)(src + off);
    const float4 a1 = *(const float4*)(src + off + 4);
    bf16x8 v;
    v[0]=(bf16)a0.x; v[1]=(bf16)a0.y; v[2]=(bf16)a0.z; v[3]=(bf16)a0.w;
    v[4]=(bf16)a1.x; v[5]=(bf16)a1.y; v[6]=(bf16)a1.z; v[7]=(bf16)a1.w;
    *(bf16x8*)(wdst + e) = v;
  }
}

// ---------- QKV projection GEMM: C[m,n] = sum_k A[m,k]*B[n,k] ----------
// 256x256 tile, BK=32 (32 K-tiles), 512 thr / 8 waves (wm 0..1, wn 0..3),
// per-wave output 128x64. 3 LDS slots, prefetch depth 2: at body kt stage
// tile kt+2 into slot (kt+2)%3 (last read at kt-1), then vmcnt(8) -> tile kt
// landed, kt+1/kt+2 in flight. 2 barriers/tile. 32 indep MFMA per tile.
// Rows are 64B (4 x 16B chunks), swizzle chunk ^ (row&3) both sides.
// grid 192 = 3z x 64 tiles; xcd = wgid&7, z-major per XCD.
__global__ __launch_bounds__(512, 2) void qkv_gemm_kernel(
    const bf16* __restrict__ xt, const bf16* __restrict__ xb,
    const bf16* __restrict__ wq, const bf16* __restrict__ wk, const bf16* __restrict__ wv,
    const float* __restrict__ bq, const float* __restrict__ bk, const float* __restrict__ bv,
    bf16* __restrict__ cq, bf16* __restrict__ ck, bf16* __restrict__ vt)
{
  __shared__ __align__(16) char LDSG[98304];   // A: 3x16KB | B: 3x16KB
  char* As = LDSG;
  char* Bs = LDSG + 49152;
  const int t = threadIdx.x, w = t >> 6, l = t & 63, g = l >> 4, c = l & 15;
  const int wm = w >> 2, wn = w & 3;
  const int wgid = blockIdx.x;
  const int xcd = wgid & 7;        // HW round-robins consecutive wgids over XCDs
  const int p = wgid >> 3;         // 0..23 per XCD, z-major
  const int z = p >> 3;            // 0..2
  const int q = p & 7;             // 0..7
  const bf16 *A, *B; const float* bias; bf16* outp;
  int tm, tn;
  if (z < 2) { tm = xcd * 2 + (q & 1); tn = q >> 1; }       // 16 x 4 tiles
  else       { tm = q >> 1; tn = xcd * 2 + (q & 1); }       // 4 x 16 tiles
  if (z == 0)      { A = xt; B = wq; bias = bq; outp = cq; }
  else if (z == 1) { A = xt; B = wk; bias = bk; outp = ck; }
  else             { A = wv; B = xb; bias = bv; outp = vt; }
  const int m0 = tm * 256, n0 = tn * 256;

  f32x4 acc[8][4] = {};   // [mf: wm*128 + mf*16][nf: wn*64 + nf*16]

  // staging: thread t covers rows lr=t>>2 and lr+128, chunk pc=t&3 (16B).
  // LDS linear dest (t*16); global source pre-swizzled: LDS(row,pc) holds
  // global chunk pc ^ (row&3) (rule #21; read side applies the same XOR).
  const int lr = t >> 2, pc = t & 3;
  const size_t ssw = (size_t)lr * 2048 + (size_t)((pc ^ (lr & 3)) << 4);
  const char* aga = (const char*)A + (size_t)m0 * 2048 + ssw;
  const char* bga = (const char*)B + (size_t)n0 * 2048 + ssw;

#define GSTAGE(slot, kt)                                                 \
  {                                                                      \
    const size_t ko = (size_t)(kt) * 64;    /* 32 k-elems * 2B */        \
    char* ad = As + (slot) * 16384 + t * 16;                             \
    char* bd = Bs + (slot) * 16384 + t * 16;                             \
    gll16(aga + ko,          ad);                                        \
    gll16(aga + ko + 262144, ad + 8192);   /* rows 128..255 */           \
    gll16(bga + ko,          bd);                                        \
    gll16(bga + ko + 262144, bd + 8192);                                 \
  }

  GSTAGE(0, 0);
  GSTAGE(1, 1);
  int st = 2;   // slot receiving tile kt+2
  int s  = 0;   // slot holding tile kt
  for (int kt = 0; kt < 32; ++kt) {
    if (kt < 30) {
      GSTAGE(st, kt + 2);
      // 4 (tile kt) + 4 (kt+1) + 4 (kt+2 just issued) outstanding at most;
      // wait to 8 -> tile kt landed, kt+1/kt+2 stay in flight.
      asm volatile("s_waitcnt vmcnt(8)" ::: "memory");
    } else if (kt == 30) {
      asm volatile("s_waitcnt vmcnt(4)" ::: "memory");
    } else {
      asm volatile("s_waitcnt vmcnt(0)" ::: "memory");
    }
    __builtin_amdgcn_sched_barrier(0);
    __builtin_amdgcn_s_barrier();          // everyone's tile-kt portion landed

    const char* Ab = As + s * 16384;
    const char* Bb = Bs + s * 16384;
    bf16x8 bfr[4], af[8];
#pragma unroll
    for (int nf = 0; nf < 4; ++nf) {
      const int row = wn * 64 + nf * 16 + c;
      bfr[nf] = *(const bf16x8*)(Bb + row * 64 + ((g ^ (row & 3)) << 4));
    }
#pragma unroll
    for (int mf = 0; mf < 8; ++mf) {
      const int row = wm * 128 + mf * 16 + c;
      af[mf] = *(const bf16x8*)(Ab + row * 64 + ((g ^ (row & 3)) << 4));
    }
    __builtin_amdgcn_s_setprio(1);
#pragma unroll
    for (int mf = 0; mf < 8; ++mf)
#pragma unroll
      for (int nf = 0; nf < 4; ++nf)
        acc[mf][nf] = __builtin_amdgcn_mfma_f32_16x16x32_bf16(af[mf], bfr[nf], acc[mf][nf], 0, 0, 0);
    __builtin_amdgcn_s_setprio(0);
    __builtin_amdgcn_s_barrier();          // slot holding kt+... free for reuse
    s  = (s  == 2) ? 0 : s + 1;
    st = (st == 2) ? 0 : st + 1;
  }
#undef GSTAGE

  // epilogue: D layout col=lane&15, row=(lane>>4)*4+r   [m89]
  if (z < 2) {
    const float sc = (z == 0) ? 0.125f * LOG2E : 1.0f;  // fold 1/sqrt(hd), log2e into cQ
#pragma unroll
    for (int mf = 0; mf < 8; ++mf)
#pragma unroll
      for (int nf = 0; nf < 4; ++nf) {
        const int n = n0 + wn * 64 + nf * 16 + c;
        const int h = n >> 6, d = n & 63;
        const float bsum = 2.0f * bias[n];
#pragma unroll
        for (int r = 0; r < 4; ++r) {
          const int m = m0 + wm * 128 + mf * 16 + g * 4 + r;
          const int b = m >> 10, s2 = m & 1023;
          outp[(((size_t)(b * 16 + h)) * 1024 + s2) * 64 + d] = (bf16)((acc[mf][nf][r] + bsum) * sc);
        }
      }
  } else {
#pragma unroll
    for (int mf = 0; mf < 8; ++mf)
#pragma unroll
      for (int nf = 0; nf < 4; ++nf) {
        const int n = n0 + wn * 64 + nf * 16 + c;   // x-row
        const int b = n >> 10, s2 = n & 1023;
#pragma unroll
        for (int r = 0; r < 4; ++r) {
          const int m = m0 + wm * 128 + mf * 16 + g * 4 + r;  // v-dim
          const int h = m >> 6, d = m & 63;
          outp[(((size_t)(b * 16 + h)) * 64 + d) * 1024 + s2] = (bf16)(acc[mf][nf][r] + bias[m]);
        }
      }
  }
}

// ---------- flash attention (swapped QK^T, permuted-K, lane-local P) ----------
// grid (16 qtiles, 64 bh), 256 threads = 4 waves, wave owns 16 q-rows.
// LDS 32KB: K dbuf 2x8KB | V dbuf 2x8KB. K staged with row permutation
// kap(kr) so that S^T row kr corresponds to PV B-slot kr; P never touches LDS.
__global__ __launch_bounds__(256) void attn_kernel(
    const bf16* __restrict__ cq, const bf16* __restrict__ ck, const bf16* __restrict__ vt,
    float* __restrict__ out)
{
  __shared__ __align__(16) char LDS[32768];
  const int t = threadIdx.x, w = t >> 6, l = t & 63, g = l >> 4, c = l & 15;
  const int bh = blockIdx.y, qt = blockIdx.x;
  const int b = bh >> 4, h = bh & 15;
  const bf16* cqb = cq + (size_t)bh * 65536;
  const bf16* ckb = ck + (size_t)bh * 65536;
  const bf16* vtb = vt + (size_t)bh * 65536;
  const int q0 = qt * 64 + w * 16;

  // Q as B-fragment: lane (g,c) holds cQ[q0+c][kf*32 + g*8 + j]
  bf16x8 qf[2];
#pragma unroll
  for (int kf = 0; kf < 2; ++kf)
    qf[kf] = *(const bf16x8*)(cqb + (size_t)(q0 + c) * 64 + kf * 32 + g * 8);

  f32x4 o[4] = {};                       // O^T: o[nd][r] = O[q=c][d=nd*16+g*4+r]
  float m = -INFINITY, lsum = 0.f;       // per q=c (replicated across g)

  const int srow = t >> 3;               // lds row 0..31 (and +32)
  const int sch  = (t & 7) ^ (srow & 7); // pre-swizzled 16B chunk
  // kap(R) for R<32 (bit5=0): ((R>>4)&1)*32 + ((R>>2)&3)*8 + (R&3);
  // kap(R+32) = kap(R) + 4.
  const int kap = ((srow >> 4) & 1) * 32 + ((srow >> 2) & 3) * 8 + (srow & 3);
  const size_t ksrc1 = (size_t)kap * 128 + (size_t)sch * 16;
  const size_t ksrc2 = ksrc1 + 512;      // +4 key rows
  const size_t vsrc  = (size_t)srow * 2048 + (size_t)sch * 16;

#define STAGE(buf, t0)                                                   \
  {                                                                      \
    const char* kgb = (const char*)ckb + (size_t)(t0) * 128;             \
    const char* vgb = (const char*)vtb + (size_t)(t0) * 2;               \
    char* kd = LDS + (buf) * 8192 + w * 1024;                            \
    char* vd = LDS + 16384 + (buf) * 8192 + w * 1024;                    \
    gll16(kgb + ksrc1,        kd);                                       \
    gll16(kgb + ksrc2,        kd + 4096);  /* lds rows 32..63 */         \
    gll16(vgb + vsrc,         vd);                                       \
    gll16(vgb + 65536 + vsrc, vd + 4096);  /* d-rows 32..63 */           \
  }

  STAGE(0, 0);
  __syncthreads();
  int buf = 0;

  for (int t0 = 0; t0 < 1024; t0 += 64) {
    if (t0 + 64 < 1024) STAGE(buf ^ 1, t0 + 64);
    const char* Kb = LDS + buf * 8192;
    const char* Vb = LDS + 16384 + buf * 8192;

    // S^T = K~.Q^T : s[nf][r] = S[slot=nf*16+g*4+r][q=c]  (log2 units),
    // slot kr holds global key t0 + kap(kr).
    f32x4 s[4] = {};
#pragma unroll
    for (int kf = 0; kf < 2; ++kf)
#pragma unroll
      for (int nf = 0; nf < 4; ++nf) {
        const int kr = nf * 16 + c;
        bf16x8 kb = *(const bf16x8*)(Kb + kr * 128 + (((kf * 4 + g) ^ (kr & 7)) << 4));
        s[nf] = __builtin_amdgcn_mfma_f32_16x16x32_bf16(kb, qf[kf], s[nf], 0, 0, 0);
      }

    // lane-local max for q=c (16 own scores) + cross-g reduce
    float vmax = s[0][0];
#pragma unroll
    for (int nf = 0; nf < 4; ++nf)
#pragma unroll
      for (int r = 0; r < 4; ++r) vmax = fmaxf(vmax, s[nf][r]);
    vmax = fmaxf(vmax, __shfl_xor(vmax, 16, 64));
    vmax = fmaxf(vmax, __shfl_xor(vmax, 32, 64));
    // defer-max (T13): skip rescale unless max grew by > 8 (log2 units)
    if (!__all(vmax - m <= 8.0f)) {
      const float mnew = fmaxf(m, vmax);
      const float alpha = exp2f(m - mnew);
      m = mnew;
      lsum *= alpha;
#pragma unroll
      for (int nd = 0; nd < 4; ++nd) o[nd] *= alpha;
    }

    float p[4][4];
    float ps = 0.f;
#pragma unroll
    for (int nf = 0; nf < 4; ++nf)
#pragma unroll
      for (int r = 0; r < 4; ++r) {
        p[nf][r] = exp2f(s[nf][r] - m);
        ps += p[nf][r];
      }
    ps += __shfl_xor(ps, 16, 64);
    ps += __shfl_xor(ps, 32, 64);
    lsum += ps;

    // PV B-fragment, fully lane-local thanks to kap permutation:
    // pa[kf] word j2 = pk(p[kf+2*(j2>>1)][2*(j2&1)], p[...][2*(j2&1)+1])
    union { unsigned u[4]; bf16x8 v; } pa0, pa1;
    pa0.u[0] = cvtpk(p[0][0], p[0][1]); pa0.u[1] = cvtpk(p[0][2], p[0][3]);
    pa0.u[2] = cvtpk(p[2][0], p[2][1]); pa0.u[3] = cvtpk(p[2][2], p[2][3]);
    pa1.u[0] = cvtpk(p[1][0], p[1][1]); pa1.u[1] = cvtpk(p[1][2], p[1][3]);
    pa1.u[2] = cvtpk(p[3][0], p[3][1]); pa1.u[3] = cvtpk(p[3][2], p[3][3]);

    // O^T += Vt.P^T : A = Vt rows d (keys in global order = slot order)
#pragma unroll
    for (int kf = 0; kf < 2; ++kf) {
      const bf16x8 pav = kf ? pa1.v : pa0.v;
#pragma unroll
      for (int nd = 0; nd < 4; ++nd) {
        const int vr = nd * 16 + c;
        bf16x8 vb = *(const bf16x8*)(Vb + vr * 128 + (((kf * 4 + g) ^ (vr & 7)) << 4));
        o[nd] = __builtin_amdgcn_mfma_f32_16x16x32_bf16(vb, pav, o[nd], 0, 0, 0);
      }
    }

    __syncthreads();   // staged buf^1 landed (vmcnt drain) + all waves done with buf
    buf ^= 1;
  }

#undef STAGE

  // epilogue: transpose O^T through LDS (reuse K region, 64x64 fp32, swizzled)
  const float inv = 1.0f / lsum;
  {
    char* Ob = LDS;  // [64 rows q][16 chunks of 16B]
    const int row = w * 16 + c;
#pragma unroll
    for (int nd = 0; nd < 4; ++nd) {
      f32x4 vo = o[nd] * inv;
      const int pch = (nd * 4 + g) ^ (row & 7);   // physical chunk
      *(f32x4*)(Ob + row * 256 + (pch << 4)) = vo;
    }
  }
  __syncthreads();
  {
    const int rr = t >> 2;                 // output row 0..63
    float* orow = out + ((size_t)(b * 1024 + qt * 64 + rr)) * 1024 + h * 64;
#pragma unroll
    for (int i = 0; i < 4; ++i) {
      const int ch = (t & 3) + i * 4;      // data chunk = d/4
      f32x4 v = *(const f32x4*)(LDS + rr * 256 + ((ch ^ (rr & 7)) << 4));
      *(f32x4*)(orow + ch * 4) = v;
    }
  }
}

extern "C" void kernel_launch(void* const* d_in, const int* in_sizes, int n_in,
                              void* d_out, int out_size, void* d_ws, size_t ws_size,
                              hipStream_t stream) {
  const float* x   = (const float*)d_in[0];
  const float* tok = (const float*)d_in[1];
  const float* Wq  = (const float*)d_in[2];
  const float* bq  = (const float*)d_in[3];
  const float* Wk  = (const float*)d_in[4];
  const float* bk  = (const float*)d_in[5];
  const float* Wv  = (const float*)d_in[6];
  const float* bv  = (const float*)d_in[7];
  float* out = (float*)d_out;
  char* ws = (char*)d_ws;
  // workspace layout (46 MB total)
  bf16* xt  = (bf16*)(ws + (size_t)0);
  bf16* xb  = (bf16*)(ws + ((size_t)8  << 20));
  bf16* wqb = (bf16*)(ws + ((size_t)16 << 20));
  bf16* wkb = (bf16*)(ws + ((size_t)18 << 20));
  bf16* wvb = (bf16*)(ws + ((size_t)20 << 20));
  bf16* cqw = (bf16*)(ws + ((size_t)22 << 20));
  bf16* ckw = (bf16*)(ws + ((size_t)30 << 20));
  bf16* vtw = (bf16*)(ws + ((size_t)38 << 20));

  prep_kernel<<<dim3(3584), dim3(256), 0, stream>>>(x, tok, Wq, Wk, Wv, xb, xt, wqb);
  qkv_gemm_kernel<<<dim3(192), dim3(512), 0, stream>>>(
      xt, xb, wqb, wkb, wvb, bq, bk, bv, cqw, ckw, vtw);
  attn_kernel<<<dim3(16, 64), dim3(256), 0, stream>>>(cqw, ckw, vtw, out);
}

// Round 8
// 87.275 us; speedup vs baseline: 1.4215x; 1.0300x over previous
//
#include <hip/hip_runtime.h>
#include <hip/hip_bf16.h>

// GuideAttentionModule: out = softmax((Q+tQ)(K+tK)^T/8) V, fused via
//   xt = x + tokens;  cQ = (xt@Wq.T + 2bq)*(0.125*log2e) ; cK = xt@Wk.T + 2bk ;
//   Vt = (x@Wv.T + bv)^T
// GEMM: 128x128 tile, BK=32, 4 waves, grid 768 = 3 blocks/CU co-resident
// (48KB LDS: 3-slot rotation, depth-2 counted vmcnt), paired-row 128B-line
// LDS layout (conflict-free ds_read_b128), XCD z-partitioned grid.
// Attention: flash, swapped QK^T with PERMUTED K staging (P fully lane-local,
// cvt_pk fragments), defer-max rescale (T13), O^T + LDS transpose epilogue.

typedef __bf16 bf16;
typedef __bf16 bf16x8 __attribute__((ext_vector_type(8)));
typedef float  f32x4  __attribute__((ext_vector_type(4)));

#define LOG2E 1.4426950408889634f

__device__ __forceinline__ void gll16(const void* g, void* l) {
  __builtin_amdgcn_global_load_lds(
      (const __attribute__((address_space(1))) unsigned int*)g,
      (__attribute__((address_space(3))) unsigned int*)l, 16, 0, 0);
}

__device__ __forceinline__ unsigned cvtpk(float a, float b) {
  unsigned r;
  asm("v_cvt_pk_bf16_f32 %0, %1, %2" : "=v"(r) : "v"(a), "v"(b));
  return r;
}

// ---------- fused prep: xb/xt (blocks 0..2047), W->bf16 (blocks 2048..3583) ----------
__global__ void prep_kernel(const float* __restrict__ x, const float* __restrict__ tok,
                            const float* __restrict__ wq, const float* __restrict__ wk,
                            const float* __restrict__ wv,
                            bf16* __restrict__ xb, bf16* __restrict__ xt,
                            bf16* __restrict__ wdst) {
  const int bid = blockIdx.x;
  if (bid < 2048) {
    const size_t e = ((size_t)bid * 256 + threadIdx.x) * 8;  // 4M elems
    const int b = (int)(e >> 20);          // S*D = 1M per batch
    const int d = (int)(e & 1023);
    const float4 a0 = *(const float4*)(x + e);
    const float4 a1 = *(const float4*)(x + e + 4);
    const float4 t0 = *(const float4*)(tok + b * 1024 + d);
    const float4 t1 = *(const float4*)(tok + b * 1024 + d + 4);
    bf16x8 vb, vt;
    vb[0]=(bf16)a0.x; vb[1]=(bf16)a0.y; vb[2]=(bf16)a0.z; vb[3]=(bf16)a0.w;
    vb[4]=(bf16)a1.x; vb[5]=(bf16)a1.y; vb[6]=(bf16)a1.z; vb[7]=(bf16)a1.w;
    vt[0]=(bf16)(a0.x+t0.x); vt[1]=(bf16)(a0.y+t0.y); vt[2]=(bf16)(a0.z+t0.z); vt[3]=(bf16)(a0.w+t0.w);
    vt[4]=(bf16)(a1.x+t1.x); vt[5]=(bf16)(a1.y+t1.y); vt[6]=(bf16)(a1.z+t1.z); vt[7]=(bf16)(a1.w+t1.w);
    *(bf16x8*)(xb + e) = vb;
    *(bf16x8*)(xt + e) = vt;
  } else {
    const size_t e = ((size_t)(bid - 2048) * 256 + threadIdx.x) * 8;  // 3M elems
    const float* src; size_t off;
    if (e < (size_t)(1u<<20))      { src = wq; off = e; }
    else if (e < (size_t)(2u<<20)) { src = wk; off = e - (1u<<20); }
    else                           { src = wv; off = e - (2u<<20); }
    const float4 a0 = *(const float4*)(src + off);
    const float4 a1 = *(const float4*)(src + off + 4);
    bf16x8 v;
    v[0]=(bf16)a0.x; v[1]=(bf16)a0.y; v[2]=(bf16)a0.z; v[3]=(bf16)a0.w;
    v[4]=(bf16)a1.x; v[5]=(bf16)a1.y; v[6]=(bf16)a1.z; v[7]=(bf16)a1.w;
    *(bf16x8*)(wdst + e) = v;
  }
}

// ---------- QKV projection GEMM: C[m,n] = sum_k A[m,k]*B[n,k] ----------
// 128x128 tile, BK=32 (32 K-tiles), 256 thr / 4 waves (wr=w>>1, wc=w&1),
// per-wave 64x64 output. 3 LDS slots (16KB each), depth-2 prefetch, counted
// vmcnt(8) (4 gll16/GSTAGE). Paired-row LDS layout: 128B line r holds m-rows
// {2r, 2r+1}; 16B slot s of line r stores (m = 2r + par, kchunk kc) with
// s = (par*4 + kc) ^ (r&7)  -> every 8-lane ds_read_b128 subgroup hits all 8
// bank-quads (conflict-free). Staging applies the inverse on the global src.
// grid 768: xcd = wgid&7, z = (wgid>>3)>>5; per-XCD ~3MB working set per z.
__global__ __launch_bounds__(256, 3) void qkv_gemm_kernel(
    const bf16* __restrict__ xt, const bf16* __restrict__ xb,
    const bf16* __restrict__ wq, const bf16* __restrict__ wk, const bf16* __restrict__ wv,
    const float* __restrict__ bq, const float* __restrict__ bk, const float* __restrict__ bv,
    bf16* __restrict__ cq, bf16* __restrict__ ck, bf16* __restrict__ vt)
{
  __shared__ __align__(16) char LDSG[49152];   // A: 3x8KB | B: 3x8KB
  char* As = LDSG;
  char* Bs = LDSG + 24576;
  const int t = threadIdx.x, w = t >> 6, l = t & 63, g = l >> 4, c = l & 15;
  const int wr = w >> 1, wc = w & 1;
  const int wgid = blockIdx.x;
  const int xcd = wgid & 7;        // HW round-robins consecutive wgids over XCDs
  const int p = wgid >> 3;         // 0..95 per XCD
  const int z = p >> 5;            // 0..2
  const int q = p & 31;            // 0..31
  const bf16 *A, *B; const float* bias; bf16* outp;
  int tm, tn;
  if (z < 2) { tm = xcd * 4 + (q & 3); tn = q >> 2; }       // 32 x 8 tiles
  else       { tm = q >> 2; tn = xcd * 4 + (q & 3); }       // 8 x 32 tiles
  if (z == 0)      { A = xt; B = wq; bias = bq; outp = cq; }
  else if (z == 1) { A = xt; B = wk; bias = bk; outp = ck; }
  else             { A = wv; B = xb; bias = bv; outp = vt; }
  const int m0 = tm * 128, n0 = tn * 128;

  f32x4 acc[4][4] = {};   // [mf: wr*64 + mf*16][nf: wc*64 + nf*16]

  // staging inverse-swizzle: thread t writes LDS byte (round j)*4096 + t*16,
  // i.e. line r = j*32 + (t>>3), slot s = t&7. u = s ^ (r&7) (r&7 == (t>>3)&7
  // since 32 = 0 mod 8); holds global m-row = 2r + (u>>2), kchunk u&3.
  const int u = (t & 7) ^ ((t >> 3) & 7);
  const size_t ssw = (size_t)(2 * (t >> 3) + (u >> 2)) * 2048 + (size_t)(u & 3) * 16;
  const char* aga = (const char*)A + (size_t)m0 * 2048 + ssw;
  const char* bga = (const char*)B + (size_t)n0 * 2048 + ssw;

#define GSTAGE(slot, kt)                                                 \
  {                                                                      \
    const size_t ko = (size_t)(kt) * 64;    /* 32 k-elems * 2B */        \
    char* ad = As + (slot) * 8192 + t * 16;                              \
    char* bd = Bs + (slot) * 8192 + t * 16;                              \
    gll16(aga + ko,          ad);                                        \
    gll16(aga + ko + 131072, ad + 4096);   /* m-rows 64..127 */          \
    gll16(bga + ko,          bd);                                        \
    gll16(bga + ko + 131072, bd + 4096);                                 \
  }

  GSTAGE(0, 0);
  GSTAGE(1, 1);
  int st = 2;   // slot receiving tile kt+2
  int s  = 0;   // slot holding tile kt
  for (int kt = 0; kt < 32; ++kt) {
    if (kt < 30) {
      GSTAGE(st, kt + 2);
      // <=4 (tile kt) + 4 (kt+1) + 4 (kt+2 just issued) outstanding;
      // wait to 8 -> tile kt landed, kt+1/kt+2 stay in flight.
      asm volatile("s_waitcnt vmcnt(8)" ::: "memory");
    } else if (kt == 30) {
      asm volatile("s_waitcnt vmcnt(4)" ::: "memory");
    } else {
      asm volatile("s_waitcnt vmcnt(0)" ::: "memory");
    }
    __builtin_amdgcn_sched_barrier(0);
    __builtin_amdgcn_s_barrier();          // everyone's tile-kt portion landed

    const char* Ab = As + s * 8192;
    const char* Bb = Bs + s * 8192;
    bf16x8 af[4], bfr[4];
#pragma unroll
    for (int mf = 0; mf < 4; ++mf) {
      const int mrow = wr * 64 + mf * 16 + c;
      af[mf] = *(const bf16x8*)(Ab + (mrow >> 1) * 128 +
                                (((((mrow & 1) << 2) + g) ^ ((mrow >> 1) & 7)) << 4));
    }
#pragma unroll
    for (int nf = 0; nf < 4; ++nf) {
      const int nrow = wc * 64 + nf * 16 + c;
      bfr[nf] = *(const bf16x8*)(Bb + (nrow >> 1) * 128 +
                                 (((((nrow & 1) << 2) + g) ^ ((nrow >> 1) & 7)) << 4));
    }
    __builtin_amdgcn_s_setprio(1);
#pragma unroll
    for (int mf = 0; mf < 4; ++mf)
#pragma unroll
      for (int nf = 0; nf < 4; ++nf)
        acc[mf][nf] = __builtin_amdgcn_mfma_f32_16x16x32_bf16(af[mf], bfr[nf], acc[mf][nf], 0, 0, 0);
    __builtin_amdgcn_s_setprio(0);
    __builtin_amdgcn_s_barrier();          // slot rotation safe
    s  = (s  == 2) ? 0 : s + 1;
    st = (st == 2) ? 0 : st + 1;
  }
#undef GSTAGE

  // epilogue: D layout col=lane&15, row=(lane>>4)*4+r   [m89]
  if (z < 2) {
    const float sc = (z == 0) ? 0.125f * LOG2E : 1.0f;  // fold 1/sqrt(hd), log2e into cQ
#pragma unroll
    for (int mf = 0; mf < 4; ++mf)
#pragma unroll
      for (int nf = 0; nf < 4; ++nf) {
        const int n = n0 + wc * 64 + nf * 16 + c;
        const int h = n >> 6, d = n & 63;
        const float bsum = 2.0f * bias[n];
#pragma unroll
        for (int r = 0; r < 4; ++r) {
          const int m = m0 + wr * 64 + mf * 16 + g * 4 + r;
          const int b = m >> 10, s2 = m & 1023;
          outp[(((size_t)(b * 16 + h)) * 1024 + s2) * 64 + d] = (bf16)((acc[mf][nf][r] + bsum) * sc);
        }
      }
  } else {
#pragma unroll
    for (int mf = 0; mf < 4; ++mf)
#pragma unroll
      for (int nf = 0; nf < 4; ++nf) {
        const int n = n0 + wc * 64 + nf * 16 + c;   // x-row
        const int b = n >> 10, s2 = n & 1023;
#pragma unroll
        for (int r = 0; r < 4; ++r) {
          const int m = m0 + wr * 64 + mf * 16 + g * 4 + r;  // v-dim
          const int h = m >> 6, d = m & 63;
          outp[(((size_t)(b * 16 + h)) * 64 + d) * 1024 + s2] = (bf16)(acc[mf][nf][r] + bias[m]);
        }
      }
  }
}

// ---------- flash attention (swapped QK^T, permuted-K, lane-local P) ----------
// grid (16 qtiles, 64 bh), 256 threads = 4 waves, wave owns 16 q-rows.
// LDS 32KB: K dbuf 2x8KB | V dbuf 2x8KB. K staged with row permutation
// kap(kr) so that S^T row kr corresponds to PV B-slot kr; P never touches LDS.
__global__ __launch_bounds__(256) void attn_kernel(
    const bf16* __restrict__ cq, const bf16* __restrict__ ck, const bf16* __restrict__ vt,
    float* __restrict__ out)
{
  __shared__ __align__(16) char LDS[32768];
  const int t = threadIdx.x, w = t >> 6, l = t & 63, g = l >> 4, c = l & 15;
  const int bh = blockIdx.y, qt = blockIdx.x;
  const int b = bh >> 4, h = bh & 15;
  const bf16* cqb = cq + (size_t)bh * 65536;
  const bf16* ckb = ck + (size_t)bh * 65536;
  const bf16* vtb = vt + (size_t)bh * 65536;
  const int q0 = qt * 64 + w * 16;

  // Q as B-fragment: lane (g,c) holds cQ[q0+c][kf*32 + g*8 + j]
  bf16x8 qf[2];
#pragma unroll
  for (int kf = 0; kf < 2; ++kf)
    qf[kf] = *(const bf16x8*)(cqb + (size_t)(q0 + c) * 64 + kf * 32 + g * 8);

  f32x4 o[4] = {};                       // O^T: o[nd][r] = O[q=c][d=nd*16+g*4+r]
  float m = -INFINITY, lsum = 0.f;       // per q=c (replicated across g)

  const int srow = t >> 3;               // lds row 0..31 (and +32)
  const int sch  = (t & 7) ^ (srow & 7); // pre-swizzled 16B chunk
  // kap(R) for R<32 (bit5=0): ((R>>4)&1)*32 + ((R>>2)&3)*8 + (R&3);
  // kap(R+32) = kap(R) + 4.
  const int kap = ((srow >> 4) & 1) * 32 + ((srow >> 2) & 3) * 8 + (srow & 3);
  const size_t ksrc1 = (size_t)kap * 128 + (size_t)sch * 16;
  const size_t ksrc2 = ksrc1 + 512;      // +4 key rows
  const size_t vsrc  = (size_t)srow * 2048 + (size_t)sch * 16;

#define STAGE(buf, t0)                                                   \
  {                                                                      \
    const char* kgb = (const char*)ckb + (size_t)(t0) * 128;             \
    const char* vgb = (const char*)vtb + (size_t)(t0) * 2;               \
    char* kd = LDS + (buf) * 8192 + w * 1024;                            \
    char* vd = LDS + 16384 + (buf) * 8192 + w * 1024;                    \
    gll16(kgb + ksrc1,        kd);                                       \
    gll16(kgb + ksrc2,        kd + 4096);  /* lds rows 32..63 */         \
    gll16(vgb + vsrc,         vd);                                       \
    gll16(vgb + 65536 + vsrc, vd + 4096);  /* d-rows 32..63 */           \
  }

  STAGE(0, 0);
  __syncthreads();
  int buf = 0;

  for (int t0 = 0; t0 < 1024; t0 += 64) {
    if (t0 + 64 < 1024) STAGE(buf ^ 1, t0 + 64);
    const char* Kb = LDS + buf * 8192;
    const char* Vb = LDS + 16384 + buf * 8192;

    // S^T = K~.Q^T : s[nf][r] = S[slot=nf*16+g*4+r][q=c]  (log2 units),
    // slot kr holds global key t0 + kap(kr).
    f32x4 s[4] = {};
#pragma unroll
    for (int kf = 0; kf < 2; ++kf)
#pragma unroll
      for (int nf = 0; nf < 4; ++nf) {
        const int kr = nf * 16 + c;
        bf16x8 kb = *(const bf16x8*)(Kb + kr * 128 + (((kf * 4 + g) ^ (kr & 7)) << 4));
        s[nf] = __builtin_amdgcn_mfma_f32_16x16x32_bf16(kb, qf[kf], s[nf], 0, 0, 0);
      }

    // lane-local max for q=c (16 own scores) + cross-g reduce
    float vmax = s[0][0];
#pragma unroll
    for (int nf = 0; nf < 4; ++nf)
#pragma unroll
      for (int r = 0; r < 4; ++r) vmax = fmaxf(vmax, s[nf][r]);
    vmax = fmaxf(vmax, __shfl_xor(vmax, 16, 64));
    vmax = fmaxf(vmax, __shfl_xor(vmax, 32, 64));
    // defer-max (T13): skip rescale unless max grew by > 8 (log2 units)
    if (!__all(vmax - m <= 8.0f)) {
      const float mnew = fmaxf(m, vmax);
      const float alpha = exp2f(m - mnew);
      m = mnew;
      lsum *= alpha;
#pragma unroll
      for (int nd = 0; nd < 4; ++nd) o[nd] *= alpha;
    }

    float p[4][4];
    float ps = 0.f;
#pragma unroll
    for (int nf = 0; nf < 4; ++nf)
#pragma unroll
      for (int r = 0; r < 4; ++r) {
        p[nf][r] = exp2f(s[nf][r] - m);
        ps += p[nf][r];
      }
    ps += __shfl_xor(ps, 16, 64);
    ps += __shfl_xor(ps, 32, 64);
    lsum += ps;

    // PV B-fragment, fully lane-local thanks to kap permutation
    union { unsigned u[4]; bf16x8 v; } pa0, pa1;
    pa0.u[0] = cvtpk(p[0][0], p[0][1]); pa0.u[1] = cvtpk(p[0][2], p[0][3]);
    pa0.u[2] = cvtpk(p[2][0], p[2][1]); pa0.u[3] = cvtpk(p[2][2], p[2][3]);
    pa1.u[0] = cvtpk(p[1][0], p[1][1]); pa1.u[1] = cvtpk(p[1][2], p[1][3]);
    pa1.u[2] = cvtpk(p[3][0], p[3][1]); pa1.u[3] = cvtpk(p[3][2], p[3][3]);

    // O^T += Vt.P^T : A = Vt rows d (keys in global order = slot order)
#pragma unroll
    for (int kf = 0; kf < 2; ++kf) {
      const bf16x8 pav = kf ? pa1.v : pa0.v;
#pragma unroll
      for (int nd = 0; nd < 4; ++nd) {
        const int vr = nd * 16 + c;
        bf16x8 vb = *(const bf16x8*)(Vb + vr * 128 + (((kf * 4 + g) ^ (vr & 7)) << 4));
        o[nd] = __builtin_amdgcn_mfma_f32_16x16x32_bf16(vb, pav, o[nd], 0, 0, 0);
      }
    }

    __syncthreads();   // staged buf^1 landed (vmcnt drain) + all waves done with buf
    buf ^= 1;
  }

#undef STAGE

  // epilogue: transpose O^T through LDS (reuse K region, 64x64 fp32, swizzled)
  const float inv = 1.0f / lsum;
  {
    char* Ob = LDS;  // [64 rows q][16 chunks of 16B]
    const int row = w * 16 + c;
#pragma unroll
    for (int nd = 0; nd < 4; ++nd) {
      f32x4 vo = o[nd] * inv;
      const int pch = (nd * 4 + g) ^ (row & 7);   // physical chunk
      *(f32x4*)(Ob + row * 256 + (pch << 4)) = vo;
    }
  }
  __syncthreads();
  {
    const int rr = t >> 2;                 // output row 0..63
    float* orow = out + ((size_t)(b * 1024 + qt * 64 + rr)) * 1024 + h * 64;
#pragma unroll
    for (int i = 0; i < 4; ++i) {
      const int ch = (t & 3) + i * 4;      // data chunk = d/4
      f32x4 v = *(const f32x4*)(LDS + rr * 256 + ((ch ^ (rr & 7)) << 4));
      *(f32x4*)(orow + ch * 4) = v;
    }
  }
}

extern "C" void kernel_launch(void* const* d_in, const int* in_sizes, int n_in,
                              void* d_out, int out_size, void* d_ws, size_t ws_size,
                              hipStream_t stream) {
  const float* x   = (const float*)d_in[0];
  const float* tok = (const float*)d_in[1];
  const float* Wq  = (const float*)d_in[2];
  const float* bq  = (const float*)d_in[3];
  const float* Wk  = (const float*)d_in[4];
  const float* bk  = (const float*)d_in[5];
  const float* Wv  = (const float*)d_in[6];
  const float* bv  = (const float*)d_in[7];
  float* out = (float*)d_out;
  char* ws = (char*)d_ws;
  // workspace layout (46 MB total)
  bf16* xt  = (bf16*)(ws + (size_t)0);
  bf16* xb  = (bf16*)(ws + ((size_t)8  << 20));
  bf16* wqb = (bf16*)(ws + ((size_t)16 << 20));
  bf16* wkb = (bf16*)(ws + ((size_t)18 << 20));
  bf16* wvb = (bf16*)(ws + ((size_t)20 << 20));
  bf16* cqw = (bf16*)(ws + ((size_t)22 << 20));
  bf16* ckw = (bf16*)(ws + ((size_t)30 << 20));
  bf16* vtw = (bf16*)(ws + ((size_t)38 << 20));

  prep_kernel<<<dim3(3584), dim3(256), 0, stream>>>(x, tok, Wq, Wk, Wv, xb, xt, wqb);
  qkv_gemm_kernel<<<dim3(768), dim3(256), 0, stream>>>(
      xt, xb, wqb, wkb, wvb, bq, bk, bv, cqw, ckw, vtw);
  attn_kernel<<<dim3(16, 64), dim3(256), 0, stream>>>(cqw, ckw, vtw, out);
}

// Round 9
// 82.606 us; speedup vs baseline: 1.5018x; 1.0565x over previous
//
#include <hip/hip_runtime.h>
#include <hip/hip_bf16.h>

// GuideAttentionModule: out = softmax((Q+tQ)(K+tK)^T/8) V, fused via
//   xt = x + tokens;  cQ = (xt@Wq.T + 2bq)*(0.125*log2e) ; cK = xt@Wk.T + 2bk ;
//   Vt = (x@Wv.T + bv)^T
// GEMM: 128x128 tile, BK=32, 4 waves, 3 blocks/CU, 3-slot depth-2 counted
// vmcnt, paired-row conflict-free LDS. (unchanged from r8)
// Attention: 8 waves / q-tile 128, 3-slot depth-2 counted-vmcnt K/V staging
// (same schedule as gemm), swapped QK^T + permuted-K (P lane-local, cvt_pk),
// defer-max (T13), O^T + LDS transpose epilogue.

typedef __bf16 bf16;
typedef __bf16 bf16x8 __attribute__((ext_vector_type(8)));
typedef float  f32x4  __attribute__((ext_vector_type(4)));

#define LOG2E 1.4426950408889634f

__device__ __forceinline__ void gll16(const void* g, void* l) {
  __builtin_amdgcn_global_load_lds(
      (const __attribute__((address_space(1))) unsigned int*)g,
      (__attribute__((address_space(3))) unsigned int*)l, 16, 0, 0);
}

__device__ __forceinline__ unsigned cvtpk(float a, float b) {
  unsigned r;
  asm("v_cvt_pk_bf16_f32 %0, %1, %2" : "=v"(r) : "v"(a), "v"(b));
  return r;
}

// ---------- fused prep: xb/xt (blocks 0..2047), W->bf16 (blocks 2048..3583) ----------
__global__ void prep_kernel(const float* __restrict__ x, const float* __restrict__ tok,
                            const float* __restrict__ wq, const float* __restrict__ wk,
                            const float* __restrict__ wv,
                            bf16* __restrict__ xb, bf16* __restrict__ xt,
                            bf16* __restrict__ wdst) {
  const int bid = blockIdx.x;
  if (bid < 2048) {
    const size_t e = ((size_t)bid * 256 + threadIdx.x) * 8;  // 4M elems
    const int b = (int)(e >> 20);          // S*D = 1M per batch
    const int d = (int)(e & 1023);
    const float4 a0 = *(const float4*)(x + e);
    const float4 a1 = *(const float4*)(x + e + 4);
    const float4 t0 = *(const float4*)(tok + b * 1024 + d);
    const float4 t1 = *(const float4*)(tok + b * 1024 + d + 4);
    bf16x8 vb, vt;
    vb[0]=(bf16)a0.x; vb[1]=(bf16)a0.y; vb[2]=(bf16)a0.z; vb[3]=(bf16)a0.w;
    vb[4]=(bf16)a1.x; vb[5]=(bf16)a1.y; vb[6]=(bf16)a1.z; vb[7]=(bf16)a1.w;
    vt[0]=(bf16)(a0.x+t0.x); vt[1]=(bf16)(a0.y+t0.y); vt[2]=(bf16)(a0.z+t0.z); vt[3]=(bf16)(a0.w+t0.w);
    vt[4]=(bf16)(a1.x+t1.x); vt[5]=(bf16)(a1.y+t1.y); vt[6]=(bf16)(a1.z+t1.z); vt[7]=(bf16)(a1.w+t1.w);
    *(bf16x8*)(xb + e) = vb;
    *(bf16x8*)(xt + e) = vt;
  } else {
    const size_t e = ((size_t)(bid - 2048) * 256 + threadIdx.x) * 8;  // 3M elems
    const float* src; size_t off;
    if (e < (size_t)(1u<<20))      { src = wq; off = e; }
    else if (e < (size_t)(2u<<20)) { src = wk; off = e - (1u<<20); }
    else                           { src = wv; off = e - (2u<<20); }
    const float4 a0 = *(const float4*)(src + off);
    const float4 a1 = *(const float4*)(src + off + 4);
    bf16x8 v;
    v[0]=(bf16)a0.x; v[1]=(bf16)a0.y; v[2]=(bf16)a0.z; v[3]=(bf16)a0.w;
    v[4]=(bf16)a1.x; v[5]=(bf16)a1.y; v[6]=(bf16)a1.z; v[7]=(bf16)a1.w;
    *(bf16x8*)(wdst + e) = v;
  }
}

// ---------- QKV projection GEMM (unchanged from r8) ----------
__global__ __launch_bounds__(256, 3) void qkv_gemm_kernel(
    const bf16* __restrict__ xt, const bf16* __restrict__ xb,
    const bf16* __restrict__ wq, const bf16* __restrict__ wk, const bf16* __restrict__ wv,
    const float* __restrict__ bq, const float* __restrict__ bk, const float* __restrict__ bv,
    bf16* __restrict__ cq, bf16* __restrict__ ck, bf16* __restrict__ vt)
{
  __shared__ __align__(16) char LDSG[49152];   // A: 3x8KB | B: 3x8KB
  char* As = LDSG;
  char* Bs = LDSG + 24576;
  const int t = threadIdx.x, w = t >> 6, l = t & 63, g = l >> 4, c = l & 15;
  const int wr = w >> 1, wc = w & 1;
  const int wgid = blockIdx.x;
  const int xcd = wgid & 7;
  const int p = wgid >> 3;
  const int z = p >> 5;
  const int q = p & 31;
  const bf16 *A, *B; const float* bias; bf16* outp;
  int tm, tn;
  if (z < 2) { tm = xcd * 4 + (q & 3); tn = q >> 2; }
  else       { tm = q >> 2; tn = xcd * 4 + (q & 3); }
  if (z == 0)      { A = xt; B = wq; bias = bq; outp = cq; }
  else if (z == 1) { A = xt; B = wk; bias = bk; outp = ck; }
  else             { A = wv; B = xb; bias = bv; outp = vt; }
  const int m0 = tm * 128, n0 = tn * 128;

  f32x4 acc[4][4] = {};

  const int u = (t & 7) ^ ((t >> 3) & 7);
  const size_t ssw = (size_t)(2 * (t >> 3) + (u >> 2)) * 2048 + (size_t)(u & 3) * 16;
  const char* aga = (const char*)A + (size_t)m0 * 2048 + ssw;
  const char* bga = (const char*)B + (size_t)n0 * 2048 + ssw;

#define GSTAGE(slot, kt)                                                 \
  {                                                                      \
    const size_t ko = (size_t)(kt) * 64;                                 \
    char* ad = As + (slot) * 8192 + t * 16;                              \
    char* bd = Bs + (slot) * 8192 + t * 16;                              \
    gll16(aga + ko,          ad);                                        \
    gll16(aga + ko + 131072, ad + 4096);                                 \
    gll16(bga + ko,          bd);                                        \
    gll16(bga + ko + 131072, bd + 4096);                                 \
  }

  GSTAGE(0, 0);
  GSTAGE(1, 1);
  int st = 2;
  int s  = 0;
  for (int kt = 0; kt < 32; ++kt) {
    if (kt < 30) {
      GSTAGE(st, kt + 2);
      asm volatile("s_waitcnt vmcnt(8)" ::: "memory");
    } else if (kt == 30) {
      asm volatile("s_waitcnt vmcnt(4)" ::: "memory");
    } else {
      asm volatile("s_waitcnt vmcnt(0)" ::: "memory");
    }
    __builtin_amdgcn_sched_barrier(0);
    __builtin_amdgcn_s_barrier();

    const char* Ab = As + s * 8192;
    const char* Bb = Bs + s * 8192;
    bf16x8 af[4], bfr[4];
#pragma unroll
    for (int mf = 0; mf < 4; ++mf) {
      const int mrow = wr * 64 + mf * 16 + c;
      af[mf] = *(const bf16x8*)(Ab + (mrow >> 1) * 128 +
                                (((((mrow & 1) << 2) + g) ^ ((mrow >> 1) & 7)) << 4));
    }
#pragma unroll
    for (int nf = 0; nf < 4; ++nf) {
      const int nrow = wc * 64 + nf * 16 + c;
      bfr[nf] = *(const bf16x8*)(Bb + (nrow >> 1) * 128 +
                                 (((((nrow & 1) << 2) + g) ^ ((nrow >> 1) & 7)) << 4));
    }
    __builtin_amdgcn_s_setprio(1);
#pragma unroll
    for (int mf = 0; mf < 4; ++mf)
#pragma unroll
      for (int nf = 0; nf < 4; ++nf)
        acc[mf][nf] = __builtin_amdgcn_mfma_f32_16x16x32_bf16(af[mf], bfr[nf], acc[mf][nf], 0, 0, 0);
    __builtin_amdgcn_s_setprio(0);
    __builtin_amdgcn_s_barrier();
    s  = (s  == 2) ? 0 : s + 1;
    st = (st == 2) ? 0 : st + 1;
  }
#undef GSTAGE

  if (z < 2) {
    const float sc = (z == 0) ? 0.125f * LOG2E : 1.0f;
#pragma unroll
    for (int mf = 0; mf < 4; ++mf)
#pragma unroll
      for (int nf = 0; nf < 4; ++nf) {
        const int n = n0 + wc * 64 + nf * 16 + c;
        const int h = n >> 6, d = n & 63;
        const float bsum = 2.0f * bias[n];
#pragma unroll
        for (int r = 0; r < 4; ++r) {
          const int m = m0 + wr * 64 + mf * 16 + g * 4 + r;
          const int b = m >> 10, s2 = m & 1023;
          outp[(((size_t)(b * 16 + h)) * 1024 + s2) * 64 + d] = (bf16)((acc[mf][nf][r] + bsum) * sc);
        }
      }
  } else {
#pragma unroll
    for (int mf = 0; mf < 4; ++mf)
#pragma unroll
      for (int nf = 0; nf < 4; ++nf) {
        const int n = n0 + wc * 64 + nf * 16 + c;
        const int b = n >> 10, s2 = n & 1023;
#pragma unroll
        for (int r = 0; r < 4; ++r) {
          const int m = m0 + wr * 64 + mf * 16 + g * 4 + r;
          const int h = m >> 6, d = m & 63;
          outp[(((size_t)(b * 16 + h)) * 64 + d) * 1024 + s2] = (bf16)(acc[mf][nf][r] + bias[m]);
        }
      }
  }
}

// ---------- flash attention: 8 waves, q-tile 128, 3-slot depth-2 staging ----------
// grid (8 qtiles, 64 bh), 512 threads = 8 waves, wave owns 16 q-rows.
// LDS 48KB: K slots 3x8KB | V slots 3x8KB. Counted vmcnt (2 loads/STAGE,
// depth 2 -> vmcnt(4)), raw s_barrier, 2 barriers/tile. K staged with row
// permutation kap(r) (S^T rows land in PV B-slot order -> P lane-local).
__global__ __launch_bounds__(512) void attn_kernel(
    const bf16* __restrict__ cq, const bf16* __restrict__ ck, const bf16* __restrict__ vt,
    float* __restrict__ out)
{
  __shared__ __align__(16) char LDS[49152];
  const int t = threadIdx.x, w = t >> 6, l = t & 63, g = l >> 4, c = l & 15;
  const int bh = blockIdx.y, qt = blockIdx.x;
  const int b = bh >> 4, h = bh & 15;
  const bf16* cqb = cq + (size_t)bh * 65536;
  const bf16* ckb = ck + (size_t)bh * 65536;
  const bf16* vtb = vt + (size_t)bh * 65536;
  const int q0 = qt * 128 + w * 16;

  // Q as B-fragment: lane (g,c) holds cQ[q0+c][kf*32 + g*8 + j]
  bf16x8 qf[2];
#pragma unroll
  for (int kf = 0; kf < 2; ++kf)
    qf[kf] = *(const bf16x8*)(cqb + (size_t)(q0 + c) * 64 + kf * 32 + g * 8);

  f32x4 o[4] = {};                       // O^T: o[nd][r] = O[q=c][d=nd*16+g*4+r]
  float m = -INFINITY, lsum = 0.f;       // per q=c (replicated across g)

  // staging: 512 threads, one K-load + one V-load each. LDS row r = t>>3
  // (0..63), chunk pc = t&7, pre-swizzled src chunk sch = pc ^ (r&7).
  // K row r holds global key kap(r) (b4->32, b3b2->8, b5->4, b1b0).
  const int r_ = t >> 3;
  const int sch = (t & 7) ^ (r_ & 7);
  const int kap = ((r_ >> 4) & 1) * 32 + ((r_ >> 2) & 3) * 8 + ((r_ >> 5) & 1) * 4 + (r_ & 3);
  const size_t ksrc = (size_t)kap * 128 + (size_t)sch * 16;
  const size_t vsrc = (size_t)r_ * 2048 + (size_t)sch * 16;

#define STAGE(slot, idx)                                                 \
  {                                                                      \
    const char* kgb = (const char*)ckb + (size_t)(idx) * 8192;           \
    const char* vgb = (const char*)vtb + (size_t)(idx) * 128;            \
    gll16(kgb + ksrc, LDS + (slot) * 8192 + t * 16);                     \
    gll16(vgb + vsrc, LDS + 24576 + (slot) * 8192 + t * 16);             \
  }

  STAGE(0, 0);
  STAGE(1, 1);
  int st = 2;   // slot receiving tile idx+2
  int s  = 0;   // slot holding tile idx
  for (int idx = 0; idx < 16; ++idx) {
    if (idx < 14) {
      STAGE(st, idx + 2);
      // <=2 (tile idx) + 2 (idx+1) + 2 (idx+2 just issued) outstanding;
      // wait to 4 -> tile idx landed, idx+1/idx+2 stay in flight.
      asm volatile("s_waitcnt vmcnt(4)" ::: "memory");
    } else if (idx == 14) {
      asm volatile("s_waitcnt vmcnt(2)" ::: "memory");
    } else {
      asm volatile("s_waitcnt vmcnt(0)" ::: "memory");
    }
    __builtin_amdgcn_sched_barrier(0);
    __builtin_amdgcn_s_barrier();          // everyone's tile-idx loads landed

    const char* Kb = LDS + s * 8192;
    const char* Vb = LDS + 24576 + s * 8192;

    // S^T = K~.Q^T : s[nf][r] = S[slot=nf*16+g*4+r][q=c]  (log2 units)
    f32x4 sv[4] = {};
#pragma unroll
    for (int kf = 0; kf < 2; ++kf)
#pragma unroll
      for (int nf = 0; nf < 4; ++nf) {
        const int kr = nf * 16 + c;
        bf16x8 kb = *(const bf16x8*)(Kb + kr * 128 + (((kf * 4 + g) ^ (kr & 7)) << 4));
        sv[nf] = __builtin_amdgcn_mfma_f32_16x16x32_bf16(kb, qf[kf], sv[nf], 0, 0, 0);
      }

    // lane-local max for q=c (16 own scores) + cross-g reduce
    float vmax = sv[0][0];
#pragma unroll
    for (int nf = 0; nf < 4; ++nf)
#pragma unroll
      for (int r = 0; r < 4; ++r) vmax = fmaxf(vmax, sv[nf][r]);
    vmax = fmaxf(vmax, __shfl_xor(vmax, 16, 64));
    vmax = fmaxf(vmax, __shfl_xor(vmax, 32, 64));
    // defer-max (T13): skip rescale unless max grew by > 8 (log2 units)
    if (!__all(vmax - m <= 8.0f)) {
      const float mnew = fmaxf(m, vmax);
      const float alpha = exp2f(m - mnew);
      m = mnew;
      lsum *= alpha;
#pragma unroll
      for (int nd = 0; nd < 4; ++nd) o[nd] *= alpha;
    }

    float p[4][4];
    float ps = 0.f;
#pragma unroll
    for (int nf = 0; nf < 4; ++nf)
#pragma unroll
      for (int r = 0; r < 4; ++r) {
        p[nf][r] = exp2f(sv[nf][r] - m);
        ps += p[nf][r];
      }
    ps += __shfl_xor(ps, 16, 64);
    ps += __shfl_xor(ps, 32, 64);
    lsum += ps;

    // PV B-fragment, fully lane-local thanks to kap permutation
    union { unsigned u[4]; bf16x8 v; } pa0, pa1;
    pa0.u[0] = cvtpk(p[0][0], p[0][1]); pa0.u[1] = cvtpk(p[0][2], p[0][3]);
    pa0.u[2] = cvtpk(p[2][0], p[2][1]); pa0.u[3] = cvtpk(p[2][2], p[2][3]);
    pa1.u[0] = cvtpk(p[1][0], p[1][1]); pa1.u[1] = cvtpk(p[1][2], p[1][3]);
    pa1.u[2] = cvtpk(p[3][0], p[3][1]); pa1.u[3] = cvtpk(p[3][2], p[3][3]);

    // O^T += Vt.P^T : A = Vt rows d (keys in global order = slot order)
#pragma unroll
    for (int kf = 0; kf < 2; ++kf) {
      const bf16x8 pav = kf ? pa1.v : pa0.v;
#pragma unroll
      for (int nd = 0; nd < 4; ++nd) {
        const int vr = nd * 16 + c;
        bf16x8 vb = *(const bf16x8*)(Vb + vr * 128 + (((kf * 4 + g) ^ (vr & 7)) << 4));
        o[nd] = __builtin_amdgcn_mfma_f32_16x16x32_bf16(vb, pav, o[nd], 0, 0, 0);
      }
    }

    __builtin_amdgcn_s_barrier();          // all waves done with slot s
    s  = (s  == 2) ? 0 : s + 1;
    st = (st == 2) ? 0 : st + 1;
  }
#undef STAGE

  // epilogue: transpose O^T through LDS (128 x 64 fp32 = 32KB, swizzled)
  const float inv = 1.0f / lsum;
  {
    char* Ob = LDS;  // [128 rows q][16 chunks of 16B]
    const int row = w * 16 + c;
#pragma unroll
    for (int nd = 0; nd < 4; ++nd) {
      f32x4 vo = o[nd] * inv;
      const int pch = (nd * 4 + g) ^ (row & 7);   // physical chunk
      *(f32x4*)(Ob + row * 256 + (pch << 4)) = vo;
    }
  }
  __syncthreads();
  {
    const int rr = t >> 2;                 // output row 0..127
    float* orow = out + ((size_t)(b * 1024 + qt * 128 + rr)) * 1024 + h * 64;
#pragma unroll
    for (int i = 0; i < 4; ++i) {
      const int ch = (t & 3) + i * 4;      // data chunk = d/4
      f32x4 v = *(const f32x4*)(LDS + rr * 256 + ((ch ^ (rr & 7)) << 4));
      *(f32x4*)(orow + ch * 4) = v;
    }
  }
}

extern "C" void kernel_launch(void* const* d_in, const int* in_sizes, int n_in,
                              void* d_out, int out_size, void* d_ws, size_t ws_size,
                              hipStream_t stream) {
  const float* x   = (const float*)d_in[0];
  const float* tok = (const float*)d_in[1];
  const float* Wq  = (const float*)d_in[2];
  const float* bq  = (const float*)d_in[3];
  const float* Wk  = (const float*)d_in[4];
  const float* bk  = (const float*)d_in[5];
  const float* Wv  = (const float*)d_in[6];
  const float* bv  = (const float*)d_in[7];
  float* out = (float*)d_out;
  char* ws = (char*)d_ws;
  // workspace layout (46 MB total)
  bf16* xt  = (bf16*)(ws + (size_t)0);
  bf16* xb  = (bf16*)(ws + ((size_t)8  << 20));
  bf16* wqb = (bf16*)(ws + ((size_t)16 << 20));
  bf16* wkb = (bf16*)(ws + ((size_t)18 << 20));
  bf16* wvb = (bf16*)(ws + ((size_t)20 << 20));
  bf16* cqw = (bf16*)(ws + ((size_t)22 << 20));
  bf16* ckw = (bf16*)(ws + ((size_t)30 << 20));
  bf16* vtw = (bf16*)(ws + ((size_t)38 << 20));

  prep_kernel<<<dim3(3584), dim3(256), 0, stream>>>(x, tok, Wq, Wk, Wv, xb, xt, wqb);
  qkv_gemm_kernel<<<dim3(768), dim3(256), 0, stream>>>(
      xt, xb, wqb, wkb, wvb, bq, bk, bv, cqw, ckw, vtw);
  attn_kernel<<<dim3(8, 64), dim3(512), 0, stream>>>(cqw, ckw, vtw, out);
}